// Round 25
// baseline (430.004 us; speedup 1.0000x reference)
//
#include <hip/hip_runtime.h>
#include <math.h>

#define LREL 0.01f
__device__ __forceinline__ float lrelu(float x) { return x > 0.f ? x : LREL * x; }
__device__ __forceinline__ float fast_tanh(float x) {
    x = fminf(fmaxf(x, -10.f), 10.f);
    float a = __expf(2.f * x);
    return (a - 1.f) / (a + 1.f);
}
__device__ __forceinline__ unsigned short f2bf(float f) {
    unsigned u = __float_as_uint(f);
    unsigned r = u + 0x7FFFu + ((u >> 16) & 1u);
    return (unsigned short)(r >> 16);
}
__device__ __forceinline__ float bf2f(unsigned short h) {
    return __uint_as_float(((unsigned)h) << 16);
}

typedef __attribute__((ext_vector_type(8))) short short8;
typedef __attribute__((ext_vector_type(4))) float f32x4;

// ======= one-shot conv-weight prep: fp32 -> split-bf16 in MFMA-ready layout =======
__global__ void __launch_bounds__(256) wprep_k(
    const float* __restrict__ e3w, const float* __restrict__ er1w,
    const float* __restrict__ d1w, const float* __restrict__ dr1w,
    const float* __restrict__ e2w, const float* __restrict__ dt1w,
    const float* __restrict__ dr2w,
    unsigned short* __restrict__ e3wH, unsigned short* __restrict__ e3wL,
    unsigned short* __restrict__ er1wH, unsigned short* __restrict__ er1wL,
    unsigned short* __restrict__ d1wH, unsigned short* __restrict__ dr1wH,
    unsigned short* __restrict__ e2wH, unsigned short* __restrict__ e2wL,
    unsigned short* __restrict__ dt1wp, unsigned short* __restrict__ dr2wp)
{
    int b = blockIdx.x, tid = threadIdx.x;
    if (b < 576) {
        int region = b / 144;
        int idx = (b % 144) * 256 + tid;           // < 36864
        int chunk = idx / 9216, r = idx % 9216;
        int col = r / 288, k = r % 288;
        int tap = k >> 5, cc = k & 31;
        int cg = chunk & 1, c2 = chunk >> 1;
        int co = cg * 32 + col, ci = c2 * 32 + cc;
        const float* w = region == 0 ? e3w : region == 1 ? er1w : region == 2 ? d1w : dr1w;
        float v = w[(co * 64 + ci) * 9 + tap];
        unsigned short h = f2bf(v);
        if (region == 0)      { e3wH[idx] = h;  e3wL[idx]  = f2bf(v - bf2f(h)); }
        else if (region == 1) { er1wH[idx] = h; er1wL[idx] = f2bf(v - bf2f(h)); }
        else if (region == 2) d1wH[idx] = h;
        else                  dr1wH[idx] = h;
    } else if (b < 704) {
        int idx = (b - 576) * 256 + tid;           // < 32768
        int cc = idx >> 13, r = idx & 8191;
        int co = r >> 7, k = r & 127;
        int ky = k >> 5, kx = (k >> 3) & 3, j = k & 7;
        float v = e2w[(co * 32 + cc * 8 + j) * 16 + ky * 4 + kx];
        unsigned short h = f2bf(v);
        e2wH[idx] = h;
        e2wL[idx] = f2bf(v - bf2f(h));
    } else if (b < 832) {
        int idx = (b - 704) * 256 + tid;           // < 32768
        int p_y = idx >> 14, ch = (idx >> 13) & 1, pqq = (idx >> 12) & 1;
        int co = (idx >> 7) & 31, ks = (idx >> 5) & 3, cc = idx & 31;
        int ci = ch * 32 + cc;
        int ky = p_y + 2 * (ks >> 1), kx = pqq + 2 * (ks & 1);
        dt1wp[idx] = f2bf(dt1w[((ci * 32 + co) << 4) + ky * 4 + kx]);
    } else {
        int idx = (b - 832) * 256 + tid;           // < 4096
        dr2wp[idx] = f2bf(dr2w[idx]);
    }
}

// ================= e1 v2: 3->32, 128x128 -> 64x64, 4x4 s2 p1, lrelu (fp32, vectorized LDS) =====
// grid 512: n = b>>3, rt = b&7 (8 out rows). All 32 co per block; float2 window + float4 weights.
// OUTPUT: NHWC bf16 hi/lo [n][64][64][32]
__global__ void __launch_bounds__(256) conv_e1_t(
    const float* __restrict__ x, const float* __restrict__ w,
    const float* __restrict__ bias,
    unsigned short* __restrict__ outH, unsigned short* __restrict__ outL)
{
    __shared__ float lin[3][18][131];
    __shared__ float lw[3][32][16];
    int b = blockIdx.x;
    int n = b >> 3, rt = b & 7;
    int tid = threadIdx.x;
    int r = tid >> 5, g = tid & 31;
    const float* inp = x + (size_t)n * 3 * 16384;

    #pragma unroll
    for (int ci = 0; ci < 3; ++ci)
        if (tid < 36) lin[ci][tid >> 1][(tid & 1) ? 129 : 0] = 0.f;
    #pragma unroll
    for (int ci = 0; ci < 3; ++ci)
        #pragma unroll
        for (int k = 0; k < 9; ++k) {
            int idx = k * 256 + tid;
            int row = idx >> 7, col = idx & 127;
            int gy = 16 * rt - 1 + row;
            float v = 0.f;
            if (gy >= 0 && gy < 128)
                v = inp[ci * 16384 + gy * 128 + col];
            lin[ci][row][col + 1] = v;
        }
    for (int i = tid; i < 1536; i += 256) {
        int ci = i >> 9, rr = i & 511, co = rr >> 4, tt = rr & 15;
        lw[ci][co][tt] = w[(co * 3 + ci) * 16 + tt];
    }
    __syncthreads();

    float acc[32][2];
    #pragma unroll
    for (int co = 0; co < 32; ++co) { acc[co][0] = acc[co][1] = 0.f; }

    #pragma unroll
    for (int ci = 0; ci < 3; ++ci) {
        // window: float2 reads; win[ky][dx] = lin[ci][2r+ky][4g+dx], dx 0..5
        float2 wl[4][3];
        #pragma unroll
        for (int ky = 0; ky < 4; ++ky)
            #pragma unroll
            for (int h = 0; h < 3; ++h)
                wl[ky][h] = *(const float2*)&lin[ci][2 * r + ky][4 * g + 2 * h];
        #pragma unroll
        for (int co = 0; co < 32; ++co) {
            const float4* wp4 = (const float4*)lw[ci][co];
            float4 w0 = wp4[0], w1 = wp4[1], w2 = wp4[2], w3 = wp4[3];
            float a0 = acc[co][0], a1 = acc[co][1];
            // ky=0 (same FMA order as before: kx 0..3, acc0 then acc1)
            a0 = fmaf(wl[0][0].x, w0.x, a0); a1 = fmaf(wl[0][1].x, w0.x, a1);
            a0 = fmaf(wl[0][0].y, w0.y, a0); a1 = fmaf(wl[0][1].y, w0.y, a1);
            a0 = fmaf(wl[0][1].x, w0.z, a0); a1 = fmaf(wl[0][2].x, w0.z, a1);
            a0 = fmaf(wl[0][1].y, w0.w, a0); a1 = fmaf(wl[0][2].y, w0.w, a1);
            // ky=1
            a0 = fmaf(wl[1][0].x, w1.x, a0); a1 = fmaf(wl[1][1].x, w1.x, a1);
            a0 = fmaf(wl[1][0].y, w1.y, a0); a1 = fmaf(wl[1][1].y, w1.y, a1);
            a0 = fmaf(wl[1][1].x, w1.z, a0); a1 = fmaf(wl[1][2].x, w1.z, a1);
            a0 = fmaf(wl[1][1].y, w1.w, a0); a1 = fmaf(wl[1][2].y, w1.w, a1);
            // ky=2
            a0 = fmaf(wl[2][0].x, w2.x, a0); a1 = fmaf(wl[2][1].x, w2.x, a1);
            a0 = fmaf(wl[2][0].y, w2.y, a0); a1 = fmaf(wl[2][1].y, w2.y, a1);
            a0 = fmaf(wl[2][1].x, w2.z, a0); a1 = fmaf(wl[2][2].x, w2.z, a1);
            a0 = fmaf(wl[2][1].y, w2.w, a0); a1 = fmaf(wl[2][2].y, w2.w, a1);
            // ky=3
            a0 = fmaf(wl[3][0].x, w3.x, a0); a1 = fmaf(wl[3][1].x, w3.x, a1);
            a0 = fmaf(wl[3][0].y, w3.y, a0); a1 = fmaf(wl[3][1].y, w3.y, a1);
            a0 = fmaf(wl[3][1].x, w3.z, a0); a1 = fmaf(wl[3][2].x, w3.z, a1);
            a0 = fmaf(wl[3][1].y, w3.w, a0); a1 = fmaf(wl[3][2].y, w3.w, a1);
            acc[co][0] = a0; acc[co][1] = a1;
        }
    }

    int oy = 8 * rt + r;
    size_t base0 = (((size_t)n * 4096 + oy * 64 + 2 * g) * 32);
    unsigned* oH0 = (unsigned*)(outH + base0);
    unsigned* oL0 = (unsigned*)(outL + base0);
    unsigned* oH1 = (unsigned*)(outH + base0 + 32);
    unsigned* oL1 = (unsigned*)(outL + base0 + 32);
    #pragma unroll
    for (int p = 0; p < 16; ++p) {
        float bva = bias[2 * p];
        float bvb = bias[2 * p + 1];
        float va0 = lrelu(acc[2 * p][0] + bva),     vb0 = lrelu(acc[2 * p + 1][0] + bvb);
        float va1 = lrelu(acc[2 * p][1] + bva),     vb1 = lrelu(acc[2 * p + 1][1] + bvb);
        unsigned short ha0 = f2bf(va0), hb0 = f2bf(vb0);
        unsigned short ha1 = f2bf(va1), hb1 = f2bf(vb1);
        oH0[p] = (unsigned)ha0 | ((unsigned)hb0 << 16);
        oH1[p] = (unsigned)ha1 | ((unsigned)hb1 << 16);
        oL0[p] = (unsigned)f2bf(va0 - bf2f(ha0)) | ((unsigned)f2bf(vb0 - bf2f(hb0)) << 16);
        oL1[p] = (unsigned)f2bf(va1 - bf2f(ha1)) | ((unsigned)f2bf(vb1 - bf2f(hb1)) << 16);
    }
}

// ================= e2 via split-bf16 MFMA v3: 512 threads, 8 waves, prepped weights =================
__global__ void __launch_bounds__(512) mfma_e2_k(
    const unsigned short* __restrict__ inH, const unsigned short* __restrict__ inL,
    const unsigned short* __restrict__ wpH, const unsigned short* __restrict__ wpL,
    const float* __restrict__ bias,
    unsigned short* __restrict__ outH, unsigned short* __restrict__ outL)
{
    __shared__ unsigned short lEH[18][34][8], lEL[18][34][8];
    __shared__ unsigned short lOH[18][34][8], lOL[18][34][8];
    __shared__ unsigned short lwH[64][136], lwL[64][136];
    int b = blockIdx.x;
    int n = b >> 2, rq = b & 3;
    int tid = threadIdx.x;
    int wv = tid >> 6, l = tid & 63;
    int l15 = l & 15, lhi = l >> 4;

    f32x4 acc[4][2];
    #pragma unroll
    for (int ct = 0; ct < 4; ++ct)
        #pragma unroll
        for (int pt = 0; pt < 2; ++pt) {
            f32x4 z = {0.f, 0.f, 0.f, 0.f};
            acc[ct][pt] = z;
        }

    for (int cc = 0; cc < 4; ++cc) {
        __syncthreads();
        for (int i = tid; i < 1188; i += 512) {
            int row = i / 66, rem = i % 66;
            int par = rem & 1, cp = rem >> 1;
            int gy = 16 * rq - 1 + row;
            int gx = 2 * cp - 1 + par;
            uint4 vH = make_uint4(0u, 0u, 0u, 0u);
            uint4 vL = make_uint4(0u, 0u, 0u, 0u);
            if (gy >= 0 && gy < 64 && gx >= 0 && gx < 64) {
                size_t gi = (((size_t)n * 4096 + gy * 64 + gx) * 32 + cc * 8);
                vH = *(const uint4*)(inH + gi);
                vL = *(const uint4*)(inL + gi);
            }
            if (par == 0) {
                *(uint4*)&lEH[row][cp][0] = vH;
                *(uint4*)&lEL[row][cp][0] = vL;
            } else {
                *(uint4*)&lOH[row][cp][0] = vH;
                *(uint4*)&lOL[row][cp][0] = vL;
            }
        }
        for (int i = tid; i < 1024; i += 512) {
            int co = i >> 4, q = i & 15;
            size_t gb = (size_t)cc * 8192 + co * 128 + q * 8;
            *(uint4*)&lwH[co][q * 8] = *(const uint4*)(wpH + gb);
            *(uint4*)&lwL[co][q * 8] = *(const uint4*)(wpL + gb);
        }
        __syncthreads();

        #pragma unroll
        for (int kg = 0; kg < 4; ++kg) {
            short8 bH[2], bL[2];
            int cpo = lhi >> 1;
            int row = 2 * wv + kg;
            #pragma unroll
            for (int pt = 0; pt < 2; ++pt) {
                int cpp = pt * 16 + l15 + cpo;
                if (lhi & 1) {
                    bH[pt] = *(const short8*)&lOH[row][cpp][0];
                    bL[pt] = *(const short8*)&lOL[row][cpp][0];
                } else {
                    bH[pt] = *(const short8*)&lEH[row][cpp][0];
                    bL[pt] = *(const short8*)&lEL[row][cpp][0];
                }
            }
            #pragma unroll
            for (int ct = 0; ct < 4; ++ct) {
                short8 aH = *(const short8*)&lwH[ct * 16 + l15][kg * 32 + lhi * 8];
                short8 aL = *(const short8*)&lwL[ct * 16 + l15][kg * 32 + lhi * 8];
                #pragma unroll
                for (int pt = 0; pt < 2; ++pt) {
                    acc[ct][pt] = __builtin_amdgcn_mfma_f32_16x16x32_bf16(aH, bH[pt], acc[ct][pt], 0, 0, 0);
                    acc[ct][pt] = __builtin_amdgcn_mfma_f32_16x16x32_bf16(aH, bL[pt], acc[ct][pt], 0, 0, 0);
                    acc[ct][pt] = __builtin_amdgcn_mfma_f32_16x16x32_bf16(aL, bH[pt], acc[ct][pt], 0, 0, 0);
                }
            }
        }
    }

    int oy = 8 * rq + wv;
    #pragma unroll
    for (int pt = 0; pt < 2; ++pt) {
        int ox = pt * 16 + l15;
        size_t base = (((size_t)n * 1024 + oy * 32 + ox) << 6);
        #pragma unroll
        for (int ct = 0; ct < 4; ++ct) {
            int co0 = ct * 16 + lhi * 4;
            #pragma unroll
            for (int jp = 0; jp < 2; ++jp) {
                float v0 = lrelu(acc[ct][pt][2 * jp]     + bias[co0 + 2 * jp]);
                float v1 = lrelu(acc[ct][pt][2 * jp + 1] + bias[co0 + 2 * jp + 1]);
                unsigned short h0 = f2bf(v0), h1 = f2bf(v1);
                *(unsigned*)(outH + base + co0 + 2 * jp) = (unsigned)h0 | ((unsigned)h1 << 16);
                *(unsigned*)(outL + base + co0 + 2 * jp) =
                    (unsigned)f2bf(v0 - bf2f(h0)) | ((unsigned)f2bf(v1 - bf2f(h1)) << 16);
            }
        }
    }
}

// ================= conv1x1 fp32 (encoder), pixel-split =================
template<int IN, int ACT, int STATS>
__global__ void __launch_bounds__(256) conv1x1_t(
    const float* __restrict__ in, const float* __restrict__ res,
    const float* __restrict__ w, const float* __restrict__ bias,
    const float* __restrict__ fin, const float* __restrict__ g,
    const float* __restrict__ beta, float* __restrict__ out,
    float* __restrict__ psum, float* __restrict__ pss)
{
    __shared__ float lw[64][64];
    __shared__ float sga[64], sbb[64];
    int b = blockIdx.x;
    int n = b >> 3, pxb = b & 7;
    int tid = threadIdx.x;
    int pxg = tid & 31, cog = tid >> 5;
    for (int i = tid; i < 4096; i += 256) {
        int co = i >> 6, ci = i & 63;
        lw[ci][co] = w[co * 64 + ci];
    }
    if (IN >= 1 && tid < 64) {
        float ga = g[tid] * fin[2 * tid + 1];
        sga[tid] = ga;
        sbb[tid] = beta[tid] - fin[2 * tid] * ga;
    }
    __syncthreads();

    size_t base = (size_t)n * 65536 + pxb * 128 + pxg * 4;
    float acc[8][4];
    #pragma unroll
    for (int co = 0; co < 8; ++co) { acc[co][0]=acc[co][1]=acc[co][2]=acc[co][3]=0.f; }
    #pragma unroll 4
    for (int ci = 0; ci < 64; ++ci) {
        float4 xv = *(const float4*)(in + base + (size_t)ci * 1024);
        float x0, x1, x2, x3;
        if (IN == 1) {
            float ga = sga[ci], bb = sbb[ci];
            x0 = fmaxf(fmaf(xv.x, ga, bb), 0.f);
            x1 = fmaxf(fmaf(xv.y, ga, bb), 0.f);
            x2 = fmaxf(fmaf(xv.z, ga, bb), 0.f);
            x3 = fmaxf(fmaf(xv.w, ga, bb), 0.f);
        } else if (IN == 2) {
            float4 rv = *(const float4*)(res + base + (size_t)ci * 1024);
            float ga = sga[ci], bb = sbb[ci];
            x0 = lrelu(rv.x + fmaf(xv.x, ga, bb));
            x1 = lrelu(rv.y + fmaf(xv.y, ga, bb));
            x2 = lrelu(rv.z + fmaf(xv.z, ga, bb));
            x3 = lrelu(rv.w + fmaf(xv.w, ga, bb));
        } else {
            x0 = xv.x; x1 = xv.y; x2 = xv.z; x3 = xv.w;
        }
        const float4* wr = (const float4*)&lw[ci][cog * 8];
        float4 wa = wr[0], wb = wr[1];
        acc[0][0] = fmaf(x0, wa.x, acc[0][0]); acc[0][1] = fmaf(x1, wa.x, acc[0][1]);
        acc[0][2] = fmaf(x2, wa.x, acc[0][2]); acc[0][3] = fmaf(x3, wa.x, acc[0][3]);
        acc[1][0] = fmaf(x0, wa.y, acc[1][0]); acc[1][1] = fmaf(x1, wa.y, acc[1][1]);
        acc[1][2] = fmaf(x2, wa.y, acc[1][2]); acc[1][3] = fmaf(x3, wa.y, acc[1][3]);
        acc[2][0] = fmaf(x0, wa.z, acc[2][0]); acc[2][1] = fmaf(x1, wa.z, acc[2][1]);
        acc[2][2] = fmaf(x2, wa.z, acc[2][2]); acc[2][3] = fmaf(x3, wa.z, acc[2][3]);
        acc[3][0] = fmaf(x0, wa.w, acc[3][0]); acc[3][1] = fmaf(x1, wa.w, acc[3][1]);
        acc[3][2] = fmaf(x2, wa.w, acc[3][2]); acc[3][3] = fmaf(x3, wa.w, acc[3][3]);
        acc[4][0] = fmaf(x0, wb.x, acc[4][0]); acc[4][1] = fmaf(x1, wb.x, acc[4][1]);
        acc[4][2] = fmaf(x2, wb.x, acc[4][2]); acc[4][3] = fmaf(x3, wb.x, acc[4][3]);
        acc[5][0] = fmaf(x0, wb.y, acc[5][0]); acc[5][1] = fmaf(x1, wb.y, acc[5][1]);
        acc[5][2] = fmaf(x2, wb.y, acc[5][2]); acc[5][3] = fmaf(x3, wb.y, acc[5][3]);
        acc[6][0] = fmaf(x0, wb.z, acc[6][0]); acc[6][1] = fmaf(x1, wb.z, acc[6][1]);
        acc[6][2] = fmaf(x2, wb.z, acc[6][2]); acc[6][3] = fmaf(x3, wb.z, acc[6][3]);
        acc[7][0] = fmaf(x0, wb.w, acc[7][0]); acc[7][1] = fmaf(x1, wb.w, acc[7][1]);
        acc[7][2] = fmaf(x2, wb.w, acc[7][2]); acc[7][3] = fmaf(x3, wb.w, acc[7][3]);
    }
    #pragma unroll
    for (int co = 0; co < 8; ++co) {
        int coG = cog * 8 + co;
        float bv = bias ? bias[coG] : 0.f;
        float a0 = acc[co][0] + bv, a1 = acc[co][1] + bv, a2 = acc[co][2] + bv, a3 = acc[co][3] + bv;
        if (ACT == 1) { a0 = lrelu(a0); a1 = lrelu(a1); a2 = lrelu(a2); a3 = lrelu(a3); }
        float4 v; v.x = a0; v.y = a1; v.z = a2; v.w = a3;
        *(float4*)(out + base + (size_t)coG * 1024) = v;
        if (STATS) {
            float s = a0 + a1 + a2 + a3;
            float q = a0*a0 + a1*a1 + a2*a2 + a3*a3;
            #pragma unroll
            for (int m = 1; m < 32; m <<= 1) {
                s += __shfl_xor(s, m);
                q += __shfl_xor(q, m);
            }
            if (pxg == 0) {
                psum[(size_t)coG * 512 + n * 8 + pxb] = s;
                pss [(size_t)coG * 512 + n * 8 + pxb] = q;
            }
        }
    }
}

// ================= BN finalize (parallel, 256 threads) =================
__global__ void bn_fin2_k(const float* __restrict__ psum, const float* __restrict__ pss,
                          float* __restrict__ fin, float invM, int cnt)
{
    __shared__ float s1[64][4], s2[64][4];
    int c = threadIdx.x >> 2, part = threadIdx.x & 3;
    int per = cnt >> 2;
    float s = 0.f, q = 0.f;
    for (int i = part * per; i < (part + 1) * per; ++i) {
        s += psum[(size_t)c * cnt + i];
        q += pss[(size_t)c * cnt + i];
    }
    s1[c][part] = s; s2[c][part] = q;
    __syncthreads();
    if (part == 0) {
        float ss = s1[c][0] + s1[c][1] + s1[c][2] + s1[c][3];
        float qq = s2[c][0] + s2[c][1] + s2[c][2] + s2[c][3];
        float mean = ss * invM;
        float var  = qq * invM - mean * mean;
        fin[2 * c] = mean;
        fin[2 * c + 1] = rsqrtf(var + 1e-5f);
    }
}

__global__ void bn_fin3_k(const float* __restrict__ psum, const float* __restrict__ pss,
                          float* __restrict__ fin, float invM)
{
    int c = threadIdx.x;
    if (c >= 64) return;
    float s = 0.f, q = 0.f;
    for (int i = 0; i < 256; ++i) { s += psum[c * 256 + i]; q += pss[c * 256 + i]; }
    float mean = s * invM;
    float var  = q * invM - mean * mean;
    fin[2 * c] = mean;
    fin[2 * c + 1] = rsqrtf(var + 1e-5f);
}

// ================= transpose NCHW fp32 -> NHWC bf16 (+optional BN-relu) =================
template<int MODE>
__global__ void __launch_bounds__(256) trans_k(
    const float* __restrict__ in, const float* __restrict__ fin,
    const float* __restrict__ g, const float* __restrict__ beta,
    unsigned short* __restrict__ outT)
{
    __shared__ unsigned short tt[256][68];
    __shared__ float sga[64], sbb[64];
    int b = blockIdx.x;
    int n = b >> 2, pxb = b & 3;
    int tid = threadIdx.x;
    if (MODE == 1) {
        if (tid < 64) {
            float ga = g[tid] * fin[2 * tid + 1];
            sga[tid] = ga;
            sbb[tid] = beta[tid] - fin[2 * tid] * ga;
        }
        __syncthreads();
    }
    for (int i = tid; i < 16384; i += 256) {
        int ci = i >> 8, px = i & 255;
        float v = in[((size_t)(n * 64 + ci) << 10) + pxb * 256 + px];
        if (MODE == 1) v = fmaxf(fmaf(v, sga[ci], sbb[ci]), 0.f);
        tt[px][ci] = f2bf(v);
    }
    __syncthreads();
    for (int o = tid; o < 4096; o += 256) {
        int px = o >> 4, c4 = o & 15;
        uint2 v = *(const uint2*)&tt[px][c4 * 4];
        *(uint2*)(outT + ((((size_t)n << 10) + pxb * 256 + px) << 6) + c4 * 4) = v;
    }
}

// ======= split-bf16 transpose: NCHW fp32 -> NHWC bf16 hi + lo =======
template<int INM>
__global__ void __launch_bounds__(256) trans_hl_k(
    const float* __restrict__ inA, const float* __restrict__ inB,
    const float* __restrict__ bias2,
    unsigned short* __restrict__ outH, unsigned short* __restrict__ outL)
{
    __shared__ unsigned short th[256][68];
    __shared__ unsigned short tl[256][68];
    __shared__ float sb[64];
    int b = blockIdx.x;
    int n = b >> 2, pxb = b & 3;
    int tid = threadIdx.x;
    if (INM == 1 && tid < 64) sb[tid] = bias2[tid];
    if (INM == 1) __syncthreads();
    for (int i = tid; i < 16384; i += 256) {
        int ci = i >> 8, px = i & 255;
        size_t gi = ((size_t)(n * 64 + ci) << 10) + pxb * 256 + px;
        float v = inA[gi];
        if (INM == 1) v = lrelu(v + inB[gi] + sb[ci]);
        unsigned short h = f2bf(v);
        th[px][ci] = h;
        tl[px][ci] = f2bf(v - bf2f(h));
    }
    __syncthreads();
    for (int o = tid; o < 4096; o += 256) {
        int px = o >> 4, c4 = o & 15;
        size_t oidx = ((((size_t)n << 10) + pxb * 256 + px) << 6) + c4 * 4;
        *(uint2*)(outH + oidx) = *(const uint2*)&th[px][c4 * 4];
        *(uint2*)(outL + oidx) = *(const uint2*)&tl[px][c4 * 4];
    }
}

// ================= fused lrelu(res + bn(x)) + NCHW fp32 -> NHWC bf16 =================
__global__ void __launch_bounds__(256) bnres_trans_k(
    const float* __restrict__ xin, const float* __restrict__ res,
    const float* __restrict__ fin, const float* __restrict__ g,
    const float* __restrict__ beta, unsigned short* __restrict__ outT)
{
    __shared__ unsigned short tt[256][68];
    __shared__ float sga[64], sbb[64];
    int b = blockIdx.x;
    int n = b >> 2, pxb = b & 3;
    int tid = threadIdx.x;
    if (tid < 64) {
        float ga = g[tid] * fin[2 * tid + 1];
        sga[tid] = ga;
        sbb[tid] = beta[tid] - fin[2 * tid] * ga;
    }
    __syncthreads();
    for (int i = tid; i < 16384; i += 256) {
        int ci = i >> 8, px = i & 255;
        size_t gi = ((size_t)(n * 64 + ci) << 10) + pxb * 256 + px;
        float v = lrelu(res[gi] + fmaf(xin[gi], sga[ci], sbb[ci]));
        tt[px][ci] = f2bf(v);
    }
    __syncthreads();
    for (int o = tid; o < 4096; o += 256) {
        int px = o >> 4, c4 = o & 15;
        uint2 v = *(const uint2*)&tt[px][c4 * 4];
        *(uint2*)(outT + ((((size_t)n << 10) + pxb * 256 + px) << 6) + c4 * 4) = v;
    }
}

// ================= MFMA conv3x3 64->64 @32x32, bf16 (decoder), 8 waves, prepped weights =================
template<int ACT, int STATS>
__global__ void __launch_bounds__(512) mfma_conv3x3_k(
    const unsigned short* __restrict__ inT, const unsigned short* __restrict__ wpH,
    const float* __restrict__ bias, float* __restrict__ out,
    float* __restrict__ psum, float* __restrict__ pss)
{
    __shared__ unsigned short lin[10][34][40];
    __shared__ unsigned short lwA[32][296];
    __shared__ float sS[8][32], sQ[8][32];
    int b = blockIdx.x;
    int cg = b & 1, pxb = (b >> 1) & 3, n = b >> 3;
    int tid = threadIdx.x;
    int wv = tid >> 6, l = tid & 63;
    int l15 = l & 15, lhi = l >> 4;

    f32x4 acc[2][2];
    #pragma unroll
    for (int ct = 0; ct < 2; ++ct)
        #pragma unroll
        for (int bt = 0; bt < 2; ++bt) {
            f32x4 z = {0.f, 0.f, 0.f, 0.f};
            acc[ct][bt] = z;
        }

    for (int c2 = 0; c2 < 2; ++c2) {
        __syncthreads();
        for (int i = tid; i < 1360; i += 512) {
            int pos = i >> 2, q = i & 3;
            int row = pos / 34, col = pos % 34;
            int iy = pxb * 8 - 1 + row, ix = col - 1;
            uint4 v = make_uint4(0u, 0u, 0u, 0u);
            if (iy >= 0 && iy < 32 && ix >= 0 && ix < 32)
                v = *(const uint4*)(inT + ((((size_t)n << 10) + iy * 32 + ix) << 6) + c2 * 32 + q * 8);
            *(uint4*)&lin[row][col][q * 8] = v;
        }
        for (int i = tid; i < 1152; i += 512) {
            int col = i / 36, q = i % 36;
            size_t gb = (size_t)(c2 * 2 + cg) * 9216 + col * 288 + q * 8;
            *(uint4*)&lwA[col][q * 8] = *(const uint4*)(wpH + gb);
        }
        __syncthreads();
        #pragma unroll
        for (int tap = 0; tap < 9; ++tap) {
            const int dy = tap / 3, dx = tap % 3;
            short8 a[2], bb[2];
            #pragma unroll
            for (int ct = 0; ct < 2; ++ct)
                a[ct] = *(const short8*)&lwA[ct * 16 + l15][tap * 32 + lhi * 8];
            #pragma unroll
            for (int bt = 0; bt < 2; ++bt)
                bb[bt] = *(const short8*)&lin[wv + dy][bt * 16 + l15 + dx][lhi * 8];
            #pragma unroll
            for (int ct = 0; ct < 2; ++ct)
                #pragma unroll
                for (int bt = 0; bt < 2; ++bt)
                    acc[ct][bt] = __builtin_amdgcn_mfma_f32_16x16x32_bf16(a[ct], bb[bt], acc[ct][bt], 0, 0, 0);
        }
    }

    int orow = pxb * 8 + wv;
    #pragma unroll
    for (int ct = 0; ct < 2; ++ct) {
        #pragma unroll
        for (int j = 0; j < 4; ++j) {
            int co_l = ct * 16 + lhi * 4 + j;
            int co = cg * 32 + co_l;
            float bv = bias ? bias[co] : 0.f;
            float s = 0.f, q = 0.f;
            #pragma unroll
            for (int bt = 0; bt < 2; ++bt) {
                float v = acc[ct][bt][j] + bv;
                if (ACT == 1) v = lrelu(v);
                int col = bt * 16 + l15;
                out[(((size_t)n * 64 + co) << 10) + orow * 32 + col] = v;
                if (STATS) { s += v; q = fmaf(v, v, q); }
            }
            if (STATS) {
                #pragma unroll
                for (int m = 1; m < 16; m <<= 1) {
                    s += __shfl_xor(s, m);
                    q += __shfl_xor(q, m);
                }
                if (l15 == 0) { sS[wv][co_l] = s; sQ[wv][co_l] = q; }
            }
        }
    }
    if (STATS) {
        __syncthreads();
        if (tid < 32) {
            float s = 0.f, q = 0.f;
            #pragma unroll
            for (int k = 0; k < 8; ++k) { s += sS[k][tid]; q += sQ[k][tid]; }
            psum[(cg * 32 + tid) * 256 + n * 4 + pxb] = s;
            pss [(cg * 32 + tid) * 256 + n * 4 + pxb] = q;
        }
    }
}

// ======= split-bf16 MFMA conv3x3 (encoder), 8 waves, prepped weights =======
template<int ACT, int STATS>
__global__ void __launch_bounds__(512) mfma_conv3x3_hl_k(
    const unsigned short* __restrict__ inH, const unsigned short* __restrict__ inL,
    const unsigned short* __restrict__ wpH, const unsigned short* __restrict__ wpL,
    const float* __restrict__ bias,
    float* __restrict__ out, float* __restrict__ psum, float* __restrict__ pss)
{
    __shared__ unsigned short linH[10][34][40];
    __shared__ unsigned short linL[10][34][40];
    __shared__ unsigned short lwH[32][296];
    __shared__ unsigned short lwL[32][296];
    __shared__ float sS[8][32], sQ[8][32];
    int b = blockIdx.x;
    int cg = b & 1, pxb = (b >> 1) & 3, n = b >> 3;
    int tid = threadIdx.x;
    int wv = tid >> 6, l = tid & 63;
    int l15 = l & 15, lhi = l >> 4;

    f32x4 acc[2][2];
    #pragma unroll
    for (int ct = 0; ct < 2; ++ct)
        #pragma unroll
        for (int bt = 0; bt < 2; ++bt) {
            f32x4 z = {0.f, 0.f, 0.f, 0.f};
            acc[ct][bt] = z;
        }

    for (int c2 = 0; c2 < 2; ++c2) {
        __syncthreads();
        for (int i = tid; i < 1360; i += 512) {
            int pos = i >> 2, q = i & 3;
            int row = pos / 34, col = pos % 34;
            int iy = pxb * 8 - 1 + row, ix = col - 1;
            uint4 vh = make_uint4(0u, 0u, 0u, 0u);
            uint4 vl = make_uint4(0u, 0u, 0u, 0u);
            if (iy >= 0 && iy < 32 && ix >= 0 && ix < 32) {
                size_t gi = ((((size_t)n << 10) + iy * 32 + ix) << 6) + c2 * 32 + q * 8;
                vh = *(const uint4*)(inH + gi);
                vl = *(const uint4*)(inL + gi);
            }
            *(uint4*)&linH[row][col][q * 8] = vh;
            *(uint4*)&linL[row][col][q * 8] = vl;
        }
        for (int i = tid; i < 1152; i += 512) {
            int col = i / 36, q = i % 36;
            size_t gb = (size_t)(c2 * 2 + cg) * 9216 + col * 288 + q * 8;
            *(uint4*)&lwH[col][q * 8] = *(const uint4*)(wpH + gb);
            *(uint4*)&lwL[col][q * 8] = *(const uint4*)(wpL + gb);
        }
        __syncthreads();
        #pragma unroll
        for (int tap = 0; tap < 9; ++tap) {
            const int dy = tap / 3, dx = tap % 3;
            short8 aH[2], aL[2], bH[2], bL[2];
            #pragma unroll
            for (int ct = 0; ct < 2; ++ct) {
                aH[ct] = *(const short8*)&lwH[ct * 16 + l15][tap * 32 + lhi * 8];
                aL[ct] = *(const short8*)&lwL[ct * 16 + l15][tap * 32 + lhi * 8];
            }
            #pragma unroll
            for (int bt = 0; bt < 2; ++bt) {
                bH[bt] = *(const short8*)&linH[wv + dy][bt * 16 + l15 + dx][lhi * 8];
                bL[bt] = *(const short8*)&linL[wv + dy][bt * 16 + l15 + dx][lhi * 8];
            }
            #pragma unroll
            for (int ct = 0; ct < 2; ++ct)
                #pragma unroll
                for (int bt = 0; bt < 2; ++bt) {
                    acc[ct][bt] = __builtin_amdgcn_mfma_f32_16x16x32_bf16(aH[ct], bH[bt], acc[ct][bt], 0, 0, 0);
                    acc[ct][bt] = __builtin_amdgcn_mfma_f32_16x16x32_bf16(aH[ct], bL[bt], acc[ct][bt], 0, 0, 0);
                    acc[ct][bt] = __builtin_amdgcn_mfma_f32_16x16x32_bf16(aL[ct], bH[bt], acc[ct][bt], 0, 0, 0);
                }
        }
    }

    int orow = pxb * 8 + wv;
    #pragma unroll
    for (int ct = 0; ct < 2; ++ct) {
        #pragma unroll
        for (int j = 0; j < 4; ++j) {
            int co_l = ct * 16 + lhi * 4 + j;
            int co = cg * 32 + co_l;
            float bv = bias ? bias[co] : 0.f;
            float s = 0.f, q = 0.f;
            #pragma unroll
            for (int bt = 0; bt < 2; ++bt) {
                float v = acc[ct][bt][j] + bv;
                if (ACT == 1) v = lrelu(v);
                int col = bt * 16 + l15;
                out[(((size_t)n * 64 + co) << 10) + orow * 32 + col] = v;
                if (STATS) { s += v; q = fmaf(v, v, q); }
            }
            if (STATS) {
                #pragma unroll
                for (int m = 1; m < 16; m <<= 1) {
                    s += __shfl_xor(s, m);
                    q += __shfl_xor(q, m);
                }
                if (l15 == 0) { sS[wv][co_l] = s; sQ[wv][co_l] = q; }
            }
        }
    }
    if (STATS) {
        __syncthreads();
        if (tid < 32) {
            float s = 0.f, q = 0.f;
            #pragma unroll
            for (int k = 0; k < 8; ++k) { s += sS[k][tid]; q += sQ[k][tid]; }
            psum[(cg * 32 + tid) * 256 + n * 4 + pxb] = s;
            pss [(cg * 32 + tid) * 256 + n * 4 + pxb] = q;
        }
    }
}

// ================= MFMA conv1x1 64->64 @32x32, bf16 (decoder), prepped weights =================
template<int ACT, int STATS>
__global__ void __launch_bounds__(256) mfma_conv1x1_k(
    const unsigned short* __restrict__ inT, const unsigned short* __restrict__ wp,
    const float* __restrict__ bias, float* __restrict__ out,
    float* __restrict__ psum, float* __restrict__ pss)
{
    __shared__ unsigned short lin[256][72];
    __shared__ unsigned short lwA[32][72];
    __shared__ float sS[4][32], sQ[4][32];
    int b = blockIdx.x;
    int cg = b & 1, pxb = (b >> 1) & 3, n = b >> 3;
    int tid = threadIdx.x;
    int wv = tid >> 6, l = tid & 63;
    int l15 = l & 15, lhi = l >> 4;

    for (int i = tid; i < 2048; i += 256) {
        int px = i >> 3, q = i & 7;
        uint4 v = *(const uint4*)(inT + ((((size_t)n << 10) + pxb * 256 + px) << 6) + q * 8);
        *(uint4*)&lin[px][q * 8] = v;
    }
    for (int i = tid; i < 256; i += 256) {
        int col = i >> 3, q = i & 7;
        *(uint4*)&lwA[col][q * 8] = *(const uint4*)(wp + (size_t)(cg * 32 + col) * 64 + q * 8);
    }
    __syncthreads();

    f32x4 acc[2][4];
    #pragma unroll
    for (int ct = 0; ct < 2; ++ct)
        #pragma unroll
        for (int bt = 0; bt < 4; ++bt) {
            f32x4 z = {0.f, 0.f, 0.f, 0.f};
            acc[ct][bt] = z;
        }

    #pragma unroll
    for (int ks = 0; ks < 2; ++ks) {
        short8 a[2], bb[4];
        #pragma unroll
        for (int ct = 0; ct < 2; ++ct)
            a[ct] = *(const short8*)&lwA[ct * 16 + l15][ks * 32 + lhi * 8];
        #pragma unroll
        for (int bt = 0; bt < 4; ++bt)
            bb[bt] = *(const short8*)&lin[wv * 64 + bt * 16 + l15][ks * 32 + lhi * 8];
        #pragma unroll
        for (int ct = 0; ct < 2; ++ct)
            #pragma unroll
            for (int bt = 0; bt < 4; ++bt)
                acc[ct][bt] = __builtin_amdgcn_mfma_f32_16x16x32_bf16(a[ct], bb[bt], acc[ct][bt], 0, 0, 0);
    }

    #pragma unroll
    for (int ct = 0; ct < 2; ++ct) {
        #pragma unroll
        for (int j = 0; j < 4; ++j) {
            int co_l = ct * 16 + lhi * 4 + j;
            int co = cg * 32 + co_l;
            float bv = bias ? bias[co] : 0.f;
            float s = 0.f, q = 0.f;
            #pragma unroll
            for (int bt = 0; bt < 4; ++bt) {
                float v = acc[ct][bt][j] + bv;
                if (ACT == 1) v = lrelu(v);
                int px = pxb * 256 + wv * 64 + bt * 16 + l15;
                out[(((size_t)n * 64 + co) << 10) + px] = v;
                if (STATS) { s += v; q = fmaf(v, v, q); }
            }
            if (STATS) {
                #pragma unroll
                for (int m = 1; m < 16; m <<= 1) {
                    s += __shfl_xor(s, m);
                    q += __shfl_xor(q, m);
                }
                if (l15 == 0) { sS[wv][co_l] = s; sQ[wv][co_l] = q; }
            }
        }
    }
    if (STATS) {
        __syncthreads();
        if (tid < 32) {
            float s = sS[0][tid] + sS[1][tid] + sS[2][tid] + sS[3][tid];
            float q = sQ[0][tid] + sQ[1][tid] + sQ[2][tid] + sQ[3][tid];
            psum[(cg * 32 + tid) * 256 + n * 4 + pxb] = s;
            pss [(cg * 32 + tid) * 256 + n * 4 + pxb] = q;
        }
    }
}

// ================= MFMA dt1: deconv 64->32, 32x32 -> 64x64, lrelu (bf16), prepped weights =================
__global__ void __launch_bounds__(256) mfma_dt1_k(
    const unsigned short* __restrict__ inT, const unsigned short* __restrict__ wp,
    const float* __restrict__ bias, float* __restrict__ out)
{
    __shared__ unsigned short lin[5][34][40];
    __shared__ unsigned short lwA[2][32][136];
    int b = blockIdx.x;
    int ublk = b & 7, p_y = (b >> 3) & 1, n = b >> 4;
    int tid = threadIdx.x;
    int wv = tid >> 6, l = tid & 63;
    int l15 = l & 15, lhi = l >> 4;
    int pq = wv & 1;
    int vbase = 1 - pq;
    int ubase = ublk * 4 + (p_y == 0 ? 1 : 0);

    f32x4 acc[2][4];
    #pragma unroll
    for (int ct = 0; ct < 2; ++ct)
        #pragma unroll
        for (int bt = 0; bt < 4; ++bt) {
            f32x4 z = {0.f, 0.f, 0.f, 0.f};
            acc[ct][bt] = z;
        }

    for (int ch = 0; ch < 2; ++ch) {
        __syncthreads();
        for (int i = tid; i < 680; i += 256) {
            int rr = i / 136, rem = i % 136;
            int jc = rem >> 2, q = rem & 3;
            int gy = ubase - 1 + rr, gx = jc - 1;
            uint4 v = make_uint4(0u, 0u, 0u, 0u);
            if (gy >= 0 && gy < 32 && gx >= 0 && gx < 32)
                v = *(const uint4*)(inT + ((((size_t)n << 10) + gy * 32 + gx) << 6) + ch * 32 + q * 8);
            *(uint4*)&lin[rr][jc][q * 8] = v;
        }
        for (int i = tid; i < 1024; i += 256) {
            int pqq = i >> 9, co = (i >> 4) & 31, q = i & 15;
            size_t gb = (size_t)(((p_y * 2 + ch) * 2 + pqq) << 12) + co * 128 + q * 8;
            *(uint4*)&lwA[pqq][co][q * 8] = *(const uint4*)(wp + gb);
        }
        __syncthreads();
        #pragma unroll
        for (int ks = 0; ks < 4; ++ks) {
            int ty = ks >> 1, tx = ks & 1;
            short8 a[2], bb[4];
            #pragma unroll
            for (int ct = 0; ct < 2; ++ct)
                a[ct] = *(const short8*)&lwA[pq][ct * 16 + l15][ks * 32 + lhi * 8];
            #pragma unroll
            for (int bt = 0; bt < 4; ++bt) {
                int jloc = (wv >> 1) * 2 + (bt >> 1);
                int vloc = (bt & 1) * 16 + l15;
                bb[bt] = *(const short8*)&lin[jloc + 1 - ty][vloc + vbase + 1 - tx][lhi * 8];
            }
            #pragma unroll
            for (int ct = 0; ct < 2; ++ct)
                #pragma unroll
                for (int bt = 0; bt < 4; ++bt)
                    acc[ct][bt] = __builtin_amdgcn_mfma_f32_16x16x32_bf16(a[ct], bb[bt], acc[ct][bt], 0, 0, 0);
        }
    }

    #pragma unroll
    for (int ct = 0; ct < 2; ++ct) {
        #pragma unroll
        for (int j = 0; j < 4; ++j) {
            int co = ct * 16 + lhi * 4 + j;
            float bv = bias[co];
            #pragma unroll
            for (int bt = 0; bt < 4; ++bt) {
                int jloc = (wv >> 1) * 2 + (bt >> 1);
                int vloc = (bt & 1) * 16 + l15;
                int oy = 2 * (ubase + jloc) - 1 + p_y;
                int ox = 2 * (vloc + vbase) - 1 + pq;
                out[((size_t)(n * 32 + co) << 12) + oy * 64 + ox] = lrelu(acc[ct][bt][j] + bv);
            }
        }
    }
}

// ================= VQ =================
__device__ __forceinline__ unsigned order_u32(float s) {
    unsigned u = __float_as_uint(s);
    return (s < 0.f) ? ~u : (u | 0x80000000u);
}
__device__ __forceinline__ unsigned long long min_u64(unsigned long long a, unsigned long long b) {
    return a < b ? a : b;
}

__global__ void __launch_bounds__(256) vq_prep_k(
    const float* __restrict__ emb,
    unsigned short* __restrict__ eH, unsigned short* __restrict__ eL,
    float* __restrict__ en)
{
    int b = blockIdx.x;
    int tid = threadIdx.x;
    int r = b * 4 + (tid >> 6);
    int d = tid & 63;
    float v = emb[r * 64 + d];
    unsigned short h = f2bf(v);
    eH[r * 64 + d] = h;
    eL[r * 64 + d] = f2bf(v - bf2f(h));
    if (tid < 4) {
        int row = b * 4 + tid;
        const float4* e4 = (const float4*)(emb + (size_t)row * 64);
        float s = 0.f;
        #pragma unroll
        for (int j = 0; j < 16; ++j) {
            float4 e = e4[j];
            s = fmaf(e.x, e.x, s); s = fmaf(e.y, e.y, s);
            s = fmaf(e.z, e.z, s); s = fmaf(e.w, e.w, s);
        }
        en[row] = s;
    }
}

// LDS rows padded to 76 (stride 38 dwords, gcd(38,32)=2 -> 2-way, free)
__global__ void __launch_bounds__(256) vq_dist_mfma_k(
    const float* __restrict__ z,
    const unsigned short* __restrict__ embH, const unsigned short* __restrict__ embL,
    const float* __restrict__ enq,
    unsigned long long* __restrict__ best)
{
    __shared__ unsigned short zH[128][76], zL[128][76];
    __shared__ unsigned short eH[128][76], eL[128][76];
    __shared__ float en[128];
    int b = blockIdx.x;
    int n = b >> 3, pxb = b & 7;
    int tid = threadIdx.x;
    int wv = tid >> 6, l = tid & 63;
    int l15 = l & 15, lhi = l >> 4;

    for (int k = 0; k < 32; ++k) {
        int idx = k * 256 + tid;
        int d = idx >> 7, px = idx & 127;
        float v = z[(size_t)n * 65536 + (size_t)d * 1024 + pxb * 128 + px];
        unsigned short h = f2bf(v);
        zH[px][d] = h;
        zL[px][d] = f2bf(v - bf2f(h));
    }

    unsigned long long bb0 = ~0ULL, bb1 = ~0ULL;

    for (int ch = 0; ch < 4; ++ch) {
        __syncthreads();
        for (int i = tid; i < 1024; i += 256) {
            int kc = i >> 3, q = i & 7;
            size_t gi = (size_t)(ch * 128 + kc) * 64 + q * 8;
            *(uint4*)&eH[kc][q * 8] = *(const uint4*)(embH + gi);
            *(uint4*)&eL[kc][q * 8] = *(const uint4*)(embL + gi);
        }
        if (tid < 128) en[tid] = enq[ch * 128 + tid];
        __syncthreads();

        #pragma unroll
        for (int pt = 0; pt < 2; ++pt) {
            int px = (wv * 2 + pt) * 16 + l15;
            short8 zh0 = *(const short8*)&zH[px][lhi * 8];
            short8 zh1 = *(const short8*)&zH[px][32 + lhi * 8];
            short8 zl0 = *(const short8*)&zL[px][lhi * 8];
            short8 zl1 = *(const short8*)&zL[px][32 + lhi * 8];
            unsigned long long bbl = (pt == 0) ? bb0 : bb1;
            #pragma unroll
            for (int ct2 = 0; ct2 < 8; ++ct2) {
                f32x4 acc = {0.f, 0.f, 0.f, 0.f};
                short8 eh0 = *(const short8*)&eH[ct2 * 16 + l15][lhi * 8];
                short8 eh1 = *(const short8*)&eH[ct2 * 16 + l15][32 + lhi * 8];
                short8 el0 = *(const short8*)&eL[ct2 * 16 + l15][lhi * 8];
                short8 el1 = *(const short8*)&eL[ct2 * 16 + l15][32 + lhi * 8];
                acc = __builtin_amdgcn_mfma_f32_16x16x32_bf16(eh0, zh0, acc, 0, 0, 0);
                acc = __builtin_amdgcn_mfma_f32_16x16x32_bf16(eh1, zh1, acc, 0, 0, 0);
                acc = __builtin_amdgcn_mfma_f32_16x16x32_bf16(eh0, zl0, acc, 0, 0, 0);
                acc = __builtin_amdgcn_mfma_f32_16x16x32_bf16(eh1, zl1, acc, 0, 0, 0);
                acc = __builtin_amdgcn_mfma_f32_16x16x32_bf16(el0, zh0, acc, 0, 0, 0);
                acc = __builtin_amdgcn_mfma_f32_16x16x32_bf16(el1, zh1, acc, 0, 0, 0);
                int kb = ch * 128 + ct2 * 16 + lhi * 4;
                #pragma unroll
                for (int j = 0; j < 4; ++j) {
                    float dist = fmaf(-2.f, acc[j], en[ct2 * 16 + lhi * 4 + j]);
                    unsigned long long p = ((unsigned long long)order_u32(dist) << 32) | (unsigned)(kb + j);
                    bbl = min_u64(bbl, p);
                }
            }
            if (pt == 0) bb0 = bbl; else bb1 = bbl;
        }
    }

    #pragma unroll
    for (int pt = 0; pt < 2; ++pt) {
        unsigned long long v = (pt == 0) ? bb0 : bb1;
        v = min_u64(v, __shfl_xor(v, 16));
        v = min_u64(v, __shfl_xor(v, 32));
        if (lhi == 0) {
            int px = (wv * 2 + pt) * 16 + l15;
            best[(size_t)n * 1024 + pxb * 128 + px] = v;
        }
    }
}

__global__ void __launch_bounds__(256) vq_combine_k(
    const float* __restrict__ z, const float* __restrict__ emb,
    const unsigned long long* __restrict__ best,
    float* __restrict__ out_q, unsigned short* __restrict__ outT,
    float* __restrict__ partials)
{
    __shared__ unsigned tq32[256][33];
    __shared__ float sh[256];
    int tid = threadIdx.x;
    int m = blockIdx.x * 256 + tid;
    unsigned long long bb = best[m];
    int bi = (int)(bb & 0x1ffu);
    int n = m >> 10, p = m & 1023;
    size_t base = (size_t)n * 65536 + p;
    const float* eb = emb + (bi << 6);
    float lsum = 0.f;
    #pragma unroll
    for (int d = 0; d < 64; d += 2) {
        float z0 = z[base + (size_t)d * 1024];
        float z1 = z[base + (size_t)(d + 1) * 1024];
        float q0 = eb[d], q1 = eb[d + 1];
        out_q[base + (size_t)d * 1024]       = q0;
        out_q[base + (size_t)(d + 1) * 1024] = q1;
        float d0 = q0 - z0, d1 = q1 - z1;
        lsum = fmaf(d0, d0, lsum);
        lsum = fmaf(d1, d1, lsum);
        tq32[tid][d >> 1] = (unsigned)f2bf(q0) | ((unsigned)f2bf(q1) << 16);
    }
    sh[tid] = lsum;
    __syncthreads();
    unsigned* oT = (unsigned*)outT;
    size_t m0 = (size_t)blockIdx.x * 256;
    #pragma unroll
    for (int k = 0; k < 32; ++k) {
        int j = k * 256 + tid;
        int px = j >> 5, c = j & 31;
        oT[(m0 + px) * 32 + c] = tq32[px][c];
    }
    for (int st = 128; st > 0; st >>= 1) {
        if (tid < st) sh[tid] += sh[tid + st];
        __syncthreads();
    }
    if (tid == 0) partials[blockIdx.x] = sh[0];
}

__global__ void vq_fin_k(const float* __restrict__ partials, float* __restrict__ out)
{
    __shared__ float sh[256];
    sh[threadIdx.x] = partials[threadIdx.x];
    __syncthreads();
    for (int st = 128; st > 0; st >>= 1) {
        if (threadIdx.x < st) sh[threadIdx.x] += sh[threadIdx.x + st];
        __syncthreads();
    }
    if (threadIdx.x == 0) out[0] = sh[0] * (0.25f / (65536.f * 64.f));
}

// ================= dt2: deconv 32->3, 64x64 -> 128x128, tanh (fp32) =================
__global__ void __launch_bounds__(256) deconv_dt2_t(
    const float* __restrict__ in, const float* __restrict__ w,
    const float* __restrict__ bias, float* __restrict__ out)
{
    __shared__ float lin[8][4][67];
    __shared__ float lw[8][3][16];
    int b = blockIdx.x;
    int n = b & 63, rt = b >> 6;
    int tid = threadIdx.x;
    int r4 = tid >> 6, g = tid & 63;
    int oy = rt * 4 + r4;
    const float* inp = in + (size_t)n * 32 * 4096;
    int iy0 = 2 * rt - 1;
    int ky0 = (oy + 1) & 1;
    int iyA = ((oy + 1 - ky0) >> 1) - iy0;
    int iyB = iyA - 1;

    if (tid < 64) lin[tid >> 3][(tid >> 1) & 3][(tid & 1) ? 65 : 0] = 0.f;

    float acc[3][2];
    #pragma unroll
    for (int co = 0; co < 3; ++co) { acc[co][0] = acc[co][1] = 0.f; }

    int scol = tid & 63, srs = tid >> 6;
    for (int cic = 0; cic < 4; ++cic) {
        __syncthreads();
        {
            int gy = iy0 + srs;
            bool ok = (gy >= 0 && gy < 64);
            #pragma unroll
            for (int k = 0; k < 8; ++k) {
                float v = ok ? inp[(cic * 8 + k) * 4096 + gy * 64 + scol] : 0.f;
                lin[k][srs][scol + 1] = v;
            }
        }
        if (tid < 128) {
            int ci = tid >> 4, tt = tid & 15;
            #pragma unroll
            for (int co = 0; co < 3; ++co)
                lw[ci][co][tt] = w[((cic * 8 + ci) * 3 + co) * 16 + tt];
        }
        __syncthreads();
        #pragma unroll 2
        for (int ci = 0; ci < 8; ++ci) {
            float vA0 = lin[ci][iyA][g],     vA1 = lin[ci][iyA][g + 1], vA2 = lin[ci][iyA][g + 2];
            float vB0 = lin[ci][iyB][g],     vB1 = lin[ci][iyB][g + 1], vB2 = lin[ci][iyB][g + 2];
            #pragma unroll
            for (int co = 0; co < 3; ++co) {
                const float4* wp = (const float4*)lw[ci][co];
                float4 wA = wp[ky0];
                float4 wB = wp[ky0 + 2];
                acc[co][0] = fmaf(vA1, wA.y, fmaf(vA0, wA.w, fmaf(vB1, wB.y, fmaf(vB0, wB.w, acc[co][0]))));
                acc[co][1] = fmaf(vA2, wA.x, fmaf(vA1, wA.z, fmaf(vB2, wB.x, fmaf(vB1, wB.z, acc[co][1]))));
            }
        }
    }
    #pragma unroll
    for (int co = 0; co < 3; ++co) {
        float bv = bias[co];
        float2 v;
        v.x = fast_tanh(acc[co][0] + bv);
        v.y = fast_tanh(acc[co][1] + bv);
        *(float2*)(out + ((size_t)(n * 3 + co) * 16384) + oy * 128 + 2 * g) = v;
    }
}

extern "C" void kernel_launch(void* const* d_in, const int* in_sizes, int n_in,
                              void* d_out, int out_size, void* d_ws, size_t ws_size,
                              hipStream_t stream)
{
    const float* x    = (const float*)d_in[0];
    const float* e1w  = (const float*)d_in[1];
    const float* e1b  = (const float*)d_in[2];
    const float* e2w  = (const float*)d_in[3];
    const float* e2b  = (const float*)d_in[4];
    const float* e3w  = (const float*)d_in[5];
    const float* e3b  = (const float*)d_in[6];
    const float* er1w = (const float*)d_in[7];
    const float* er1g = (const float*)d_in[8];
    const float* er1b = (const float*)d_in[9];
    const float* er2w = (const float*)d_in[10];
    const float* er2g = (const float*)d_in[11];
    const float* er2b = (const float*)d_in[12];
    const float* e4w  = (const float*)d_in[13];
    const float* e4b  = (const float*)d_in[14];
    const float* emb  = (const float*)d_in[15];
    const float* d1w  = (const float*)d_in[16];
    const float* d1b  = (const float*)d_in[17];
    const float* dr1w = (const float*)d_in[18];
    const float* dr1g = (const float*)d_in[19];
    const float* dr1b = (const float*)d_in[20];
    const float* dr2w = (const float*)d_in[21];
    const float* dr2g = (const float*)d_in[22];
    const float* dr2b = (const float*)d_in[23];
    const float* dt1w = (const float*)d_in[24];
    const float* dt1b = (const float*)d_in[25];
    const float* dt2w = (const float*)d_in[26];
    const float* dt2b = (const float*)d_in[27];

    float* out = (float*)d_out;
    float* ws  = (float*)d_ws;

    // workspace layout (floats)
    float* B0 = ws;                   // 8,388,608
    float* B1 = ws + 8388608;         // 4,194,304
    float* B2 = B1 + 4194304;
    float* B3 = B2 + 4194304;
    float* B4 = B3 + 4194304;
    float* psum   = B4 + 4194304;     // 32768
    float* pss    = psum + 32768;     // 32768
    float* fin    = pss + 32768;      // 128
    float* vq_part = fin + 128;       // 256
    unsigned long long* bestbuf = (unsigned long long*)(vq_part + 256);  // 65536 u64 = 512KB
    unsigned short* embH = (unsigned short*)(bestbuf + 65536);           // 32768 ushorts
    unsigned short* embL = embH + 32768;                                 // 32768 ushorts
    float* enq = (float*)(embL + 32768);                                 // 512 floats
    unsigned short* e3wH  = (unsigned short*)(enq + 512);                // 36864
    unsigned short* e3wL  = e3wH + 36864;
    unsigned short* er1wH = e3wL + 36864;
    unsigned short* er1wL = er1wH + 36864;
    unsigned short* d1wH  = er1wL + 36864;
    unsigned short* dr1wH = d1wH + 36864;
    unsigned short* e2wH  = dr1wH + 36864;                               // 32768
    unsigned short* e2wL  = e2wH + 32768;
    unsigned short* dt1wp = e2wL + 32768;                                // 32768
    unsigned short* dr2wp = dt1wp + 32768;                               // 4096

    unsigned short* e1H  = (unsigned short*)B0;            // 8,388,608 ushorts
    unsigned short* e1L  = e1H + 8388608;                  // 8,388,608 ushorts
    unsigned short* tbuf  = (unsigned short*)B1;           // decoder NHWC bf16
    unsigned short* tbufH = (unsigned short*)B3;           // encoder split-bf16 hi
    unsigned short* tbufL = (unsigned short*)B4;           // encoder split-bf16 lo

    float* out_recon = out;                 // 3,145,728
    float* out_q     = out + 3145728;       // 4,194,304
    float* out_e     = out + 7340032;       // 4,194,304 (scratch until e4 writes)
    float* out_loss  = out + 11534336;      // 1

    const float invM = 1.f / 65536.f;

    // ---------------- preps ----------------
    wprep_k<<<848, 256, 0, stream>>>(e3w, er1w, d1w, dr1w, e2w, dt1w, dr2w,
                                     e3wH, e3wL, er1wH, er1wL, d1wH, dr1wH, e2wH, e2wL,
                                     dt1wp, dr2wp);
    vq_prep_k<<<128, 256, 0, stream>>>(emb, embH, embL, enq);

    // ---------------- encoder ----------------
    conv_e1_t<<<512, 256, 0, stream>>>(x, e1w, e1b, e1H, e1L);
    mfma_e2_k<<<256, 512, 0, stream>>>(e1H, e1L, e2wH, e2wL, e2b, tbufH, tbufL);

    mfma_conv3x3_hl_k<1,0><<<512, 512, 0, stream>>>(tbufH, tbufL, e3wH, e3wL, e3b, B2, nullptr, nullptr);

    trans_hl_k<0><<<256, 256, 0, stream>>>(B2, nullptr, nullptr, tbufH, tbufL);
    mfma_conv3x3_hl_k<0,1><<<512, 512, 0, stream>>>(tbufH, tbufL, er1wH, er1wL, nullptr, B1, psum, pss);
    bn_fin3_k<<<1, 64, 0, stream>>>(psum, pss, fin, invM);

    conv1x1_t<1,0,1><<<512, 256, 0, stream>>>(B1, nullptr, er2w, nullptr, fin, er1g, er1b, B4, psum, pss);
    bn_fin2_k<<<1, 256, 0, stream>>>(psum, pss, fin, invM, 512);
    conv1x1_t<2,1,0><<<512, 256, 0, stream>>>(B4, B2, e4w, e4b, fin, er2g, er2b, out_e, nullptr, nullptr);

    // VQ
    vq_dist_mfma_k<<<512, 256, 0, stream>>>(out_e, embH, embL, enq, bestbuf);
    vq_combine_k<<<256, 256, 0, stream>>>(out_e, emb, bestbuf, out_q, tbuf, vq_part);
    vq_fin_k<<<1, 256, 0, stream>>>(vq_part, out_loss);

    // ---------------- decoder (bf16 MFMA) ----------------
    mfma_conv3x3_k<1,0><<<512, 512, 0, stream>>>(tbuf, d1wH, d1b, B2, nullptr, nullptr);

    trans_k<0><<<256, 256, 0, stream>>>(B2, nullptr, nullptr, nullptr, tbuf);
    mfma_conv3x3_k<0,1><<<512, 512, 0, stream>>>(tbuf, dr1wH, nullptr, B3, psum, pss);
    bn_fin3_k<<<1, 64, 0, stream>>>(psum, pss, fin, invM);

    trans_k<1><<<256, 256, 0, stream>>>(B3, fin, dr1g, dr1b, tbuf);
    mfma_conv1x1_k<0,1><<<512, 256, 0, stream>>>(tbuf, dr2wp, nullptr, B4, psum, pss);
    bn_fin3_k<<<1, 64, 0, stream>>>(psum, pss, fin, invM);

    bnres_trans_k<<<256, 256, 0, stream>>>(B4, B2, fin, dr2g, dr2b, tbuf);
    mfma_dt1_k<<<1024, 256, 0, stream>>>(tbuf, dt1wp, dt1b, B0);

    deconv_dt2_t<<<2048, 256, 0, stream>>>(B0, dt2w, dt2b, out_recon);
}

// Round 26
// 419.921 us; speedup vs baseline: 1.0240x; 1.0240x over previous
//
#include <hip/hip_runtime.h>
#include <math.h>

#define LREL 0.01f
__device__ __forceinline__ float lrelu(float x) { return x > 0.f ? x : LREL * x; }
__device__ __forceinline__ float fast_tanh(float x) {
    x = fminf(fmaxf(x, -10.f), 10.f);
    float a = __expf(2.f * x);
    return (a - 1.f) / (a + 1.f);
}
__device__ __forceinline__ unsigned short f2bf(float f) {
    unsigned u = __float_as_uint(f);
    unsigned r = u + 0x7FFFu + ((u >> 16) & 1u);
    return (unsigned short)(r >> 16);
}
__device__ __forceinline__ float bf2f(unsigned short h) {
    return __uint_as_float(((unsigned)h) << 16);
}

typedef __attribute__((ext_vector_type(8))) short short8;
typedef __attribute__((ext_vector_type(4))) float f32x4;

// ======= one-shot conv-weight prep: fp32 -> split-bf16 in MFMA-ready layout =======
__global__ void __launch_bounds__(256) wprep_k(
    const float* __restrict__ e3w, const float* __restrict__ er1w,
    const float* __restrict__ d1w, const float* __restrict__ dr1w,
    const float* __restrict__ e2w, const float* __restrict__ dt1w,
    const float* __restrict__ dr2w,
    unsigned short* __restrict__ e3wH, unsigned short* __restrict__ e3wL,
    unsigned short* __restrict__ er1wH, unsigned short* __restrict__ er1wL,
    unsigned short* __restrict__ d1wH, unsigned short* __restrict__ dr1wH,
    unsigned short* __restrict__ e2wH, unsigned short* __restrict__ e2wL,
    unsigned short* __restrict__ dt1wp, unsigned short* __restrict__ dr2wp)
{
    int b = blockIdx.x, tid = threadIdx.x;
    if (b < 576) {
        int region = b / 144;
        int idx = (b % 144) * 256 + tid;           // < 36864
        int chunk = idx / 9216, r = idx % 9216;
        int col = r / 288, k = r % 288;
        int tap = k >> 5, cc = k & 31;
        int cg = chunk & 1, c2 = chunk >> 1;
        int co = cg * 32 + col, ci = c2 * 32 + cc;
        const float* w = region == 0 ? e3w : region == 1 ? er1w : region == 2 ? d1w : dr1w;
        float v = w[(co * 64 + ci) * 9 + tap];
        unsigned short h = f2bf(v);
        if (region == 0)      { e3wH[idx] = h;  e3wL[idx]  = f2bf(v - bf2f(h)); }
        else if (region == 1) { er1wH[idx] = h; er1wL[idx] = f2bf(v - bf2f(h)); }
        else if (region == 2) d1wH[idx] = h;
        else                  dr1wH[idx] = h;
    } else if (b < 704) {
        int idx = (b - 576) * 256 + tid;           // < 32768
        int cc = idx >> 13, r = idx & 8191;
        int co = r >> 7, k = r & 127;
        int ky = k >> 5, kx = (k >> 3) & 3, j = k & 7;
        float v = e2w[(co * 32 + cc * 8 + j) * 16 + ky * 4 + kx];
        unsigned short h = f2bf(v);
        e2wH[idx] = h;
        e2wL[idx] = f2bf(v - bf2f(h));
    } else if (b < 832) {
        int idx = (b - 704) * 256 + tid;           // < 32768
        int p_y = idx >> 14, ch = (idx >> 13) & 1, pqq = (idx >> 12) & 1;
        int co = (idx >> 7) & 31, ks = (idx >> 5) & 3, cc = idx & 31;
        int ci = ch * 32 + cc;
        int ky = p_y + 2 * (ks >> 1), kx = pqq + 2 * (ks & 1);
        dt1wp[idx] = f2bf(dt1w[((ci * 32 + co) << 4) + ky * 4 + kx]);
    } else {
        int idx = (b - 832) * 256 + tid;           // < 4096
        dr2wp[idx] = f2bf(dr2w[idx]);
    }
}

// ================= e1 v3: 3->32, 128x128 -> 64x64, 4x4 s2 p1, lrelu =================
// grid 1024 (R24 geometry: 16 co/block, low VGPR) + vectorized LDS reads (R25 mechanism).
// OUTPUT: NHWC bf16 hi/lo [n][64][64][32]
__global__ void __launch_bounds__(256) conv_e1_t(
    const float* __restrict__ x, const float* __restrict__ w,
    const float* __restrict__ bias,
    unsigned short* __restrict__ outH, unsigned short* __restrict__ outL)
{
    __shared__ float lin[3][18][131];
    __shared__ float lw[3][16][16];
    int b = blockIdx.x;
    int n = b & 63, t = b >> 6;
    int rt = t & 7, cg = t >> 3;
    int tid = threadIdx.x;
    int r = tid >> 5, g = tid & 31;
    const float* inp = x + (size_t)n * 3 * 16384;

    #pragma unroll
    for (int ci = 0; ci < 3; ++ci)
        if (tid < 36) lin[ci][tid >> 1][(tid & 1) ? 129 : 0] = 0.f;
    #pragma unroll
    for (int ci = 0; ci < 3; ++ci)
        #pragma unroll
        for (int k = 0; k < 9; ++k) {
            int idx = k * 256 + tid;
            int row = idx >> 7, col = idx & 127;
            int gy = 16 * rt - 1 + row;
            float v = 0.f;
            if (gy >= 0 && gy < 128)
                v = inp[ci * 16384 + gy * 128 + col];
            lin[ci][row][col + 1] = v;
        }
    for (int i = tid; i < 768; i += 256) {
        int ci = i >> 8, rr = i & 255, co = rr >> 4, tt = rr & 15;
        lw[ci][co][tt] = w[((cg * 16 + co) * 3 + ci) * 16 + tt];
    }
    __syncthreads();

    float acc[16][2];
    #pragma unroll
    for (int co = 0; co < 16; ++co) { acc[co][0] = acc[co][1] = 0.f; }

    #pragma unroll
    for (int ci = 0; ci < 3; ++ci) {
        // window: float2 reads; win[ky][dx] = lin[ci][2r+ky][4g+dx], dx 0..5
        float2 wl[4][3];
        #pragma unroll
        for (int ky = 0; ky < 4; ++ky)
            #pragma unroll
            for (int h = 0; h < 3; ++h)
                wl[ky][h] = *(const float2*)&lin[ci][2 * r + ky][4 * g + 2 * h];
        #pragma unroll
        for (int co = 0; co < 16; ++co) {
            const float4* wp4 = (const float4*)lw[ci][co];
            float4 w0 = wp4[0], w1 = wp4[1], w2 = wp4[2], w3 = wp4[3];
            float a0 = acc[co][0], a1 = acc[co][1];
            // ky=0 (same FMA order as scalar version: kx 0..3)
            a0 = fmaf(wl[0][0].x, w0.x, a0); a1 = fmaf(wl[0][1].x, w0.x, a1);
            a0 = fmaf(wl[0][0].y, w0.y, a0); a1 = fmaf(wl[0][1].y, w0.y, a1);
            a0 = fmaf(wl[0][1].x, w0.z, a0); a1 = fmaf(wl[0][2].x, w0.z, a1);
            a0 = fmaf(wl[0][1].y, w0.w, a0); a1 = fmaf(wl[0][2].y, w0.w, a1);
            // ky=1
            a0 = fmaf(wl[1][0].x, w1.x, a0); a1 = fmaf(wl[1][1].x, w1.x, a1);
            a0 = fmaf(wl[1][0].y, w1.y, a0); a1 = fmaf(wl[1][1].y, w1.y, a1);
            a0 = fmaf(wl[1][1].x, w1.z, a0); a1 = fmaf(wl[1][2].x, w1.z, a1);
            a0 = fmaf(wl[1][1].y, w1.w, a0); a1 = fmaf(wl[1][2].y, w1.w, a1);
            // ky=2
            a0 = fmaf(wl[2][0].x, w2.x, a0); a1 = fmaf(wl[2][1].x, w2.x, a1);
            a0 = fmaf(wl[2][0].y, w2.y, a0); a1 = fmaf(wl[2][1].y, w2.y, a1);
            a0 = fmaf(wl[2][1].x, w2.z, a0); a1 = fmaf(wl[2][2].x, w2.z, a1);
            a0 = fmaf(wl[2][1].y, w2.w, a0); a1 = fmaf(wl[2][2].y, w2.w, a1);
            // ky=3
            a0 = fmaf(wl[3][0].x, w3.x, a0); a1 = fmaf(wl[3][1].x, w3.x, a1);
            a0 = fmaf(wl[3][0].y, w3.y, a0); a1 = fmaf(wl[3][1].y, w3.y, a1);
            a0 = fmaf(wl[3][1].x, w3.z, a0); a1 = fmaf(wl[3][2].x, w3.z, a1);
            a0 = fmaf(wl[3][1].y, w3.w, a0); a1 = fmaf(wl[3][2].y, w3.w, a1);
            acc[co][0] = a0; acc[co][1] = a1;
        }
    }

    int oy = 8 * rt + r;
    size_t base0 = (((size_t)n * 4096 + oy * 64 + 2 * g) * 32 + cg * 16);
    unsigned* oH0 = (unsigned*)(outH + base0);
    unsigned* oL0 = (unsigned*)(outL + base0);
    unsigned* oH1 = (unsigned*)(outH + base0 + 32);
    unsigned* oL1 = (unsigned*)(outL + base0 + 32);
    #pragma unroll
    for (int p = 0; p < 8; ++p) {
        float bva = bias[cg * 16 + 2 * p];
        float bvb = bias[cg * 16 + 2 * p + 1];
        float va0 = lrelu(acc[2 * p][0] + bva),     vb0 = lrelu(acc[2 * p + 1][0] + bvb);
        float va1 = lrelu(acc[2 * p][1] + bva),     vb1 = lrelu(acc[2 * p + 1][1] + bvb);
        unsigned short ha0 = f2bf(va0), hb0 = f2bf(vb0);
        unsigned short ha1 = f2bf(va1), hb1 = f2bf(vb1);
        oH0[p] = (unsigned)ha0 | ((unsigned)hb0 << 16);
        oH1[p] = (unsigned)ha1 | ((unsigned)hb1 << 16);
        oL0[p] = (unsigned)f2bf(va0 - bf2f(ha0)) | ((unsigned)f2bf(vb0 - bf2f(hb0)) << 16);
        oL1[p] = (unsigned)f2bf(va1 - bf2f(ha1)) | ((unsigned)f2bf(vb1 - bf2f(hb1)) << 16);
    }
}

// ================= e2 via split-bf16 MFMA v3: 512 threads, 8 waves, prepped weights =================
__global__ void __launch_bounds__(512) mfma_e2_k(
    const unsigned short* __restrict__ inH, const unsigned short* __restrict__ inL,
    const unsigned short* __restrict__ wpH, const unsigned short* __restrict__ wpL,
    const float* __restrict__ bias,
    unsigned short* __restrict__ outH, unsigned short* __restrict__ outL)
{
    __shared__ unsigned short lEH[18][34][8], lEL[18][34][8];
    __shared__ unsigned short lOH[18][34][8], lOL[18][34][8];
    __shared__ unsigned short lwH[64][136], lwL[64][136];
    int b = blockIdx.x;
    int n = b >> 2, rq = b & 3;
    int tid = threadIdx.x;
    int wv = tid >> 6, l = tid & 63;
    int l15 = l & 15, lhi = l >> 4;

    f32x4 acc[4][2];
    #pragma unroll
    for (int ct = 0; ct < 4; ++ct)
        #pragma unroll
        for (int pt = 0; pt < 2; ++pt) {
            f32x4 z = {0.f, 0.f, 0.f, 0.f};
            acc[ct][pt] = z;
        }

    for (int cc = 0; cc < 4; ++cc) {
        __syncthreads();
        for (int i = tid; i < 1188; i += 512) {
            int row = i / 66, rem = i % 66;
            int par = rem & 1, cp = rem >> 1;
            int gy = 16 * rq - 1 + row;
            int gx = 2 * cp - 1 + par;
            uint4 vH = make_uint4(0u, 0u, 0u, 0u);
            uint4 vL = make_uint4(0u, 0u, 0u, 0u);
            if (gy >= 0 && gy < 64 && gx >= 0 && gx < 64) {
                size_t gi = (((size_t)n * 4096 + gy * 64 + gx) * 32 + cc * 8);
                vH = *(const uint4*)(inH + gi);
                vL = *(const uint4*)(inL + gi);
            }
            if (par == 0) {
                *(uint4*)&lEH[row][cp][0] = vH;
                *(uint4*)&lEL[row][cp][0] = vL;
            } else {
                *(uint4*)&lOH[row][cp][0] = vH;
                *(uint4*)&lOL[row][cp][0] = vL;
            }
        }
        for (int i = tid; i < 1024; i += 512) {
            int co = i >> 4, q = i & 15;
            size_t gb = (size_t)cc * 8192 + co * 128 + q * 8;
            *(uint4*)&lwH[co][q * 8] = *(const uint4*)(wpH + gb);
            *(uint4*)&lwL[co][q * 8] = *(const uint4*)(wpL + gb);
        }
        __syncthreads();

        #pragma unroll
        for (int kg = 0; kg < 4; ++kg) {
            short8 bH[2], bL[2];
            int cpo = lhi >> 1;
            int row = 2 * wv + kg;
            #pragma unroll
            for (int pt = 0; pt < 2; ++pt) {
                int cpp = pt * 16 + l15 + cpo;
                if (lhi & 1) {
                    bH[pt] = *(const short8*)&lOH[row][cpp][0];
                    bL[pt] = *(const short8*)&lOL[row][cpp][0];
                } else {
                    bH[pt] = *(const short8*)&lEH[row][cpp][0];
                    bL[pt] = *(const short8*)&lEL[row][cpp][0];
                }
            }
            #pragma unroll
            for (int ct = 0; ct < 4; ++ct) {
                short8 aH = *(const short8*)&lwH[ct * 16 + l15][kg * 32 + lhi * 8];
                short8 aL = *(const short8*)&lwL[ct * 16 + l15][kg * 32 + lhi * 8];
                #pragma unroll
                for (int pt = 0; pt < 2; ++pt) {
                    acc[ct][pt] = __builtin_amdgcn_mfma_f32_16x16x32_bf16(aH, bH[pt], acc[ct][pt], 0, 0, 0);
                    acc[ct][pt] = __builtin_amdgcn_mfma_f32_16x16x32_bf16(aH, bL[pt], acc[ct][pt], 0, 0, 0);
                    acc[ct][pt] = __builtin_amdgcn_mfma_f32_16x16x32_bf16(aL, bH[pt], acc[ct][pt], 0, 0, 0);
                }
            }
        }
    }

    int oy = 8 * rq + wv;
    #pragma unroll
    for (int pt = 0; pt < 2; ++pt) {
        int ox = pt * 16 + l15;
        size_t base = (((size_t)n * 1024 + oy * 32 + ox) << 6);
        #pragma unroll
        for (int ct = 0; ct < 4; ++ct) {
            int co0 = ct * 16 + lhi * 4;
            #pragma unroll
            for (int jp = 0; jp < 2; ++jp) {
                float v0 = lrelu(acc[ct][pt][2 * jp]     + bias[co0 + 2 * jp]);
                float v1 = lrelu(acc[ct][pt][2 * jp + 1] + bias[co0 + 2 * jp + 1]);
                unsigned short h0 = f2bf(v0), h1 = f2bf(v1);
                *(unsigned*)(outH + base + co0 + 2 * jp) = (unsigned)h0 | ((unsigned)h1 << 16);
                *(unsigned*)(outL + base + co0 + 2 * jp) =
                    (unsigned)f2bf(v0 - bf2f(h0)) | ((unsigned)f2bf(v1 - bf2f(h1)) << 16);
            }
        }
    }
}

// ================= conv1x1 fp32 (encoder), pixel-split =================
template<int IN, int ACT, int STATS>
__global__ void __launch_bounds__(256) conv1x1_t(
    const float* __restrict__ in, const float* __restrict__ res,
    const float* __restrict__ w, const float* __restrict__ bias,
    const float* __restrict__ fin, const float* __restrict__ g,
    const float* __restrict__ beta, float* __restrict__ out,
    float* __restrict__ psum, float* __restrict__ pss)
{
    __shared__ float lw[64][64];
    __shared__ float sga[64], sbb[64];
    int b = blockIdx.x;
    int n = b >> 3, pxb = b & 7;
    int tid = threadIdx.x;
    int pxg = tid & 31, cog = tid >> 5;
    for (int i = tid; i < 4096; i += 256) {
        int co = i >> 6, ci = i & 63;
        lw[ci][co] = w[co * 64 + ci];
    }
    if (IN >= 1 && tid < 64) {
        float ga = g[tid] * fin[2 * tid + 1];
        sga[tid] = ga;
        sbb[tid] = beta[tid] - fin[2 * tid] * ga;
    }
    __syncthreads();

    size_t base = (size_t)n * 65536 + pxb * 128 + pxg * 4;
    float acc[8][4];
    #pragma unroll
    for (int co = 0; co < 8; ++co) { acc[co][0]=acc[co][1]=acc[co][2]=acc[co][3]=0.f; }
    #pragma unroll 4
    for (int ci = 0; ci < 64; ++ci) {
        float4 xv = *(const float4*)(in + base + (size_t)ci * 1024);
        float x0, x1, x2, x3;
        if (IN == 1) {
            float ga = sga[ci], bb = sbb[ci];
            x0 = fmaxf(fmaf(xv.x, ga, bb), 0.f);
            x1 = fmaxf(fmaf(xv.y, ga, bb), 0.f);
            x2 = fmaxf(fmaf(xv.z, ga, bb), 0.f);
            x3 = fmaxf(fmaf(xv.w, ga, bb), 0.f);
        } else if (IN == 2) {
            float4 rv = *(const float4*)(res + base + (size_t)ci * 1024);
            float ga = sga[ci], bb = sbb[ci];
            x0 = lrelu(rv.x + fmaf(xv.x, ga, bb));
            x1 = lrelu(rv.y + fmaf(xv.y, ga, bb));
            x2 = lrelu(rv.z + fmaf(xv.z, ga, bb));
            x3 = lrelu(rv.w + fmaf(xv.w, ga, bb));
        } else {
            x0 = xv.x; x1 = xv.y; x2 = xv.z; x3 = xv.w;
        }
        const float4* wr = (const float4*)&lw[ci][cog * 8];
        float4 wa = wr[0], wb = wr[1];
        acc[0][0] = fmaf(x0, wa.x, acc[0][0]); acc[0][1] = fmaf(x1, wa.x, acc[0][1]);
        acc[0][2] = fmaf(x2, wa.x, acc[0][2]); acc[0][3] = fmaf(x3, wa.x, acc[0][3]);
        acc[1][0] = fmaf(x0, wa.y, acc[1][0]); acc[1][1] = fmaf(x1, wa.y, acc[1][1]);
        acc[1][2] = fmaf(x2, wa.y, acc[1][2]); acc[1][3] = fmaf(x3, wa.y, acc[1][3]);
        acc[2][0] = fmaf(x0, wa.z, acc[2][0]); acc[2][1] = fmaf(x1, wa.z, acc[2][1]);
        acc[2][2] = fmaf(x2, wa.z, acc[2][2]); acc[2][3] = fmaf(x3, wa.z, acc[2][3]);
        acc[3][0] = fmaf(x0, wa.w, acc[3][0]); acc[3][1] = fmaf(x1, wa.w, acc[3][1]);
        acc[3][2] = fmaf(x2, wa.w, acc[3][2]); acc[3][3] = fmaf(x3, wa.w, acc[3][3]);
        acc[4][0] = fmaf(x0, wb.x, acc[4][0]); acc[4][1] = fmaf(x1, wb.x, acc[4][1]);
        acc[4][2] = fmaf(x2, wb.x, acc[4][2]); acc[4][3] = fmaf(x3, wb.x, acc[4][3]);
        acc[5][0] = fmaf(x0, wb.y, acc[5][0]); acc[5][1] = fmaf(x1, wb.y, acc[5][1]);
        acc[5][2] = fmaf(x2, wb.y, acc[5][2]); acc[5][3] = fmaf(x3, wb.y, acc[5][3]);
        acc[6][0] = fmaf(x0, wb.z, acc[6][0]); acc[6][1] = fmaf(x1, wb.z, acc[6][1]);
        acc[6][2] = fmaf(x2, wb.z, acc[6][2]); acc[6][3] = fmaf(x3, wb.z, acc[6][3]);
        acc[7][0] = fmaf(x0, wb.w, acc[7][0]); acc[7][1] = fmaf(x1, wb.w, acc[7][1]);
        acc[7][2] = fmaf(x2, wb.w, acc[7][2]); acc[7][3] = fmaf(x3, wb.w, acc[7][3]);
    }
    #pragma unroll
    for (int co = 0; co < 8; ++co) {
        int coG = cog * 8 + co;
        float bv = bias ? bias[coG] : 0.f;
        float a0 = acc[co][0] + bv, a1 = acc[co][1] + bv, a2 = acc[co][2] + bv, a3 = acc[co][3] + bv;
        if (ACT == 1) { a0 = lrelu(a0); a1 = lrelu(a1); a2 = lrelu(a2); a3 = lrelu(a3); }
        float4 v; v.x = a0; v.y = a1; v.z = a2; v.w = a3;
        *(float4*)(out + base + (size_t)coG * 1024) = v;
        if (STATS) {
            float s = a0 + a1 + a2 + a3;
            float q = a0*a0 + a1*a1 + a2*a2 + a3*a3;
            #pragma unroll
            for (int m = 1; m < 32; m <<= 1) {
                s += __shfl_xor(s, m);
                q += __shfl_xor(q, m);
            }
            if (pxg == 0) {
                psum[(size_t)coG * 512 + n * 8 + pxb] = s;
                pss [(size_t)coG * 512 + n * 8 + pxb] = q;
            }
        }
    }
}

// ================= BN finalize (parallel, 256 threads) =================
__global__ void bn_fin2_k(const float* __restrict__ psum, const float* __restrict__ pss,
                          float* __restrict__ fin, float invM, int cnt)
{
    __shared__ float s1[64][4], s2[64][4];
    int c = threadIdx.x >> 2, part = threadIdx.x & 3;
    int per = cnt >> 2;
    float s = 0.f, q = 0.f;
    for (int i = part * per; i < (part + 1) * per; ++i) {
        s += psum[(size_t)c * cnt + i];
        q += pss[(size_t)c * cnt + i];
    }
    s1[c][part] = s; s2[c][part] = q;
    __syncthreads();
    if (part == 0) {
        float ss = s1[c][0] + s1[c][1] + s1[c][2] + s1[c][3];
        float qq = s2[c][0] + s2[c][1] + s2[c][2] + s2[c][3];
        float mean = ss * invM;
        float var  = qq * invM - mean * mean;
        fin[2 * c] = mean;
        fin[2 * c + 1] = rsqrtf(var + 1e-5f);
    }
}

__global__ void bn_fin3_k(const float* __restrict__ psum, const float* __restrict__ pss,
                          float* __restrict__ fin, float invM)
{
    int c = threadIdx.x;
    if (c >= 64) return;
    float s = 0.f, q = 0.f;
    for (int i = 0; i < 256; ++i) { s += psum[c * 256 + i]; q += pss[c * 256 + i]; }
    float mean = s * invM;
    float var  = q * invM - mean * mean;
    fin[2 * c] = mean;
    fin[2 * c + 1] = rsqrtf(var + 1e-5f);
}

// ================= transpose NCHW fp32 -> NHWC bf16 (+optional BN-relu) =================
template<int MODE>
__global__ void __launch_bounds__(256) trans_k(
    const float* __restrict__ in, const float* __restrict__ fin,
    const float* __restrict__ g, const float* __restrict__ beta,
    unsigned short* __restrict__ outT)
{
    __shared__ unsigned short tt[256][68];
    __shared__ float sga[64], sbb[64];
    int b = blockIdx.x;
    int n = b >> 2, pxb = b & 3;
    int tid = threadIdx.x;
    if (MODE == 1) {
        if (tid < 64) {
            float ga = g[tid] * fin[2 * tid + 1];
            sga[tid] = ga;
            sbb[tid] = beta[tid] - fin[2 * tid] * ga;
        }
        __syncthreads();
    }
    for (int i = tid; i < 16384; i += 256) {
        int ci = i >> 8, px = i & 255;
        float v = in[((size_t)(n * 64 + ci) << 10) + pxb * 256 + px];
        if (MODE == 1) v = fmaxf(fmaf(v, sga[ci], sbb[ci]), 0.f);
        tt[px][ci] = f2bf(v);
    }
    __syncthreads();
    for (int o = tid; o < 4096; o += 256) {
        int px = o >> 4, c4 = o & 15;
        uint2 v = *(const uint2*)&tt[px][c4 * 4];
        *(uint2*)(outT + ((((size_t)n << 10) + pxb * 256 + px) << 6) + c4 * 4) = v;
    }
}

// ======= split-bf16 transpose: NCHW fp32 -> NHWC bf16 hi + lo =======
template<int INM>
__global__ void __launch_bounds__(256) trans_hl_k(
    const float* __restrict__ inA, const float* __restrict__ inB,
    const float* __restrict__ bias2,
    unsigned short* __restrict__ outH, unsigned short* __restrict__ outL)
{
    __shared__ unsigned short th[256][68];
    __shared__ unsigned short tl[256][68];
    __shared__ float sb[64];
    int b = blockIdx.x;
    int n = b >> 2, pxb = b & 3;
    int tid = threadIdx.x;
    if (INM == 1 && tid < 64) sb[tid] = bias2[tid];
    if (INM == 1) __syncthreads();
    for (int i = tid; i < 16384; i += 256) {
        int ci = i >> 8, px = i & 255;
        size_t gi = ((size_t)(n * 64 + ci) << 10) + pxb * 256 + px;
        float v = inA[gi];
        if (INM == 1) v = lrelu(v + inB[gi] + sb[ci]);
        unsigned short h = f2bf(v);
        th[px][ci] = h;
        tl[px][ci] = f2bf(v - bf2f(h));
    }
    __syncthreads();
    for (int o = tid; o < 4096; o += 256) {
        int px = o >> 4, c4 = o & 15;
        size_t oidx = ((((size_t)n << 10) + pxb * 256 + px) << 6) + c4 * 4;
        *(uint2*)(outH + oidx) = *(const uint2*)&th[px][c4 * 4];
        *(uint2*)(outL + oidx) = *(const uint2*)&tl[px][c4 * 4];
    }
}

// ================= fused lrelu(res + bn(x)) + NCHW fp32 -> NHWC bf16 =================
__global__ void __launch_bounds__(256) bnres_trans_k(
    const float* __restrict__ xin, const float* __restrict__ res,
    const float* __restrict__ fin, const float* __restrict__ g,
    const float* __restrict__ beta, unsigned short* __restrict__ outT)
{
    __shared__ unsigned short tt[256][68];
    __shared__ float sga[64], sbb[64];
    int b = blockIdx.x;
    int n = b >> 2, pxb = b & 3;
    int tid = threadIdx.x;
    if (tid < 64) {
        float ga = g[tid] * fin[2 * tid + 1];
        sga[tid] = ga;
        sbb[tid] = beta[tid] - fin[2 * tid] * ga;
    }
    __syncthreads();
    for (int i = tid; i < 16384; i += 256) {
        int ci = i >> 8, px = i & 255;
        size_t gi = ((size_t)(n * 64 + ci) << 10) + pxb * 256 + px;
        float v = lrelu(res[gi] + fmaf(xin[gi], sga[ci], sbb[ci]));
        tt[px][ci] = f2bf(v);
    }
    __syncthreads();
    for (int o = tid; o < 4096; o += 256) {
        int px = o >> 4, c4 = o & 15;
        uint2 v = *(const uint2*)&tt[px][c4 * 4];
        *(uint2*)(outT + ((((size_t)n << 10) + pxb * 256 + px) << 6) + c4 * 4) = v;
    }
}

// ================= MFMA conv3x3 64->64 @32x32, bf16 (decoder), 8 waves, prepped weights =================
template<int ACT, int STATS>
__global__ void __launch_bounds__(512) mfma_conv3x3_k(
    const unsigned short* __restrict__ inT, const unsigned short* __restrict__ wpH,
    const float* __restrict__ bias, float* __restrict__ out,
    float* __restrict__ psum, float* __restrict__ pss)
{
    __shared__ unsigned short lin[10][34][40];
    __shared__ unsigned short lwA[32][296];
    __shared__ float sS[8][32], sQ[8][32];
    int b = blockIdx.x;
    int cg = b & 1, pxb = (b >> 1) & 3, n = b >> 3;
    int tid = threadIdx.x;
    int wv = tid >> 6, l = tid & 63;
    int l15 = l & 15, lhi = l >> 4;

    f32x4 acc[2][2];
    #pragma unroll
    for (int ct = 0; ct < 2; ++ct)
        #pragma unroll
        for (int bt = 0; bt < 2; ++bt) {
            f32x4 z = {0.f, 0.f, 0.f, 0.f};
            acc[ct][bt] = z;
        }

    for (int c2 = 0; c2 < 2; ++c2) {
        __syncthreads();
        for (int i = tid; i < 1360; i += 512) {
            int pos = i >> 2, q = i & 3;
            int row = pos / 34, col = pos % 34;
            int iy = pxb * 8 - 1 + row, ix = col - 1;
            uint4 v = make_uint4(0u, 0u, 0u, 0u);
            if (iy >= 0 && iy < 32 && ix >= 0 && ix < 32)
                v = *(const uint4*)(inT + ((((size_t)n << 10) + iy * 32 + ix) << 6) + c2 * 32 + q * 8);
            *(uint4*)&lin[row][col][q * 8] = v;
        }
        for (int i = tid; i < 1152; i += 512) {
            int col = i / 36, q = i % 36;
            size_t gb = (size_t)(c2 * 2 + cg) * 9216 + col * 288 + q * 8;
            *(uint4*)&lwA[col][q * 8] = *(const uint4*)(wpH + gb);
        }
        __syncthreads();
        #pragma unroll
        for (int tap = 0; tap < 9; ++tap) {
            const int dy = tap / 3, dx = tap % 3;
            short8 a[2], bb[2];
            #pragma unroll
            for (int ct = 0; ct < 2; ++ct)
                a[ct] = *(const short8*)&lwA[ct * 16 + l15][tap * 32 + lhi * 8];
            #pragma unroll
            for (int bt = 0; bt < 2; ++bt)
                bb[bt] = *(const short8*)&lin[wv + dy][bt * 16 + l15 + dx][lhi * 8];
            #pragma unroll
            for (int ct = 0; ct < 2; ++ct)
                #pragma unroll
                for (int bt = 0; bt < 2; ++bt)
                    acc[ct][bt] = __builtin_amdgcn_mfma_f32_16x16x32_bf16(a[ct], bb[bt], acc[ct][bt], 0, 0, 0);
        }
    }

    int orow = pxb * 8 + wv;
    #pragma unroll
    for (int ct = 0; ct < 2; ++ct) {
        #pragma unroll
        for (int j = 0; j < 4; ++j) {
            int co_l = ct * 16 + lhi * 4 + j;
            int co = cg * 32 + co_l;
            float bv = bias ? bias[co] : 0.f;
            float s = 0.f, q = 0.f;
            #pragma unroll
            for (int bt = 0; bt < 2; ++bt) {
                float v = acc[ct][bt][j] + bv;
                if (ACT == 1) v = lrelu(v);
                int col = bt * 16 + l15;
                out[(((size_t)n * 64 + co) << 10) + orow * 32 + col] = v;
                if (STATS) { s += v; q = fmaf(v, v, q); }
            }
            if (STATS) {
                #pragma unroll
                for (int m = 1; m < 16; m <<= 1) {
                    s += __shfl_xor(s, m);
                    q += __shfl_xor(q, m);
                }
                if (l15 == 0) { sS[wv][co_l] = s; sQ[wv][co_l] = q; }
            }
        }
    }
    if (STATS) {
        __syncthreads();
        if (tid < 32) {
            float s = 0.f, q = 0.f;
            #pragma unroll
            for (int k = 0; k < 8; ++k) { s += sS[k][tid]; q += sQ[k][tid]; }
            psum[(cg * 32 + tid) * 256 + n * 4 + pxb] = s;
            pss [(cg * 32 + tid) * 256 + n * 4 + pxb] = q;
        }
    }
}

// ======= split-bf16 MFMA conv3x3 (encoder), 8 waves, prepped weights =======
template<int ACT, int STATS>
__global__ void __launch_bounds__(512) mfma_conv3x3_hl_k(
    const unsigned short* __restrict__ inH, const unsigned short* __restrict__ inL,
    const unsigned short* __restrict__ wpH, const unsigned short* __restrict__ wpL,
    const float* __restrict__ bias,
    float* __restrict__ out, float* __restrict__ psum, float* __restrict__ pss)
{
    __shared__ unsigned short linH[10][34][40];
    __shared__ unsigned short linL[10][34][40];
    __shared__ unsigned short lwH[32][296];
    __shared__ unsigned short lwL[32][296];
    __shared__ float sS[8][32], sQ[8][32];
    int b = blockIdx.x;
    int cg = b & 1, pxb = (b >> 1) & 3, n = b >> 3;
    int tid = threadIdx.x;
    int wv = tid >> 6, l = tid & 63;
    int l15 = l & 15, lhi = l >> 4;

    f32x4 acc[2][2];
    #pragma unroll
    for (int ct = 0; ct < 2; ++ct)
        #pragma unroll
        for (int bt = 0; bt < 2; ++bt) {
            f32x4 z = {0.f, 0.f, 0.f, 0.f};
            acc[ct][bt] = z;
        }

    for (int c2 = 0; c2 < 2; ++c2) {
        __syncthreads();
        for (int i = tid; i < 1360; i += 512) {
            int pos = i >> 2, q = i & 3;
            int row = pos / 34, col = pos % 34;
            int iy = pxb * 8 - 1 + row, ix = col - 1;
            uint4 vh = make_uint4(0u, 0u, 0u, 0u);
            uint4 vl = make_uint4(0u, 0u, 0u, 0u);
            if (iy >= 0 && iy < 32 && ix >= 0 && ix < 32) {
                size_t gi = ((((size_t)n << 10) + iy * 32 + ix) << 6) + c2 * 32 + q * 8;
                vh = *(const uint4*)(inH + gi);
                vl = *(const uint4*)(inL + gi);
            }
            *(uint4*)&linH[row][col][q * 8] = vh;
            *(uint4*)&linL[row][col][q * 8] = vl;
        }
        for (int i = tid; i < 1152; i += 512) {
            int col = i / 36, q = i % 36;
            size_t gb = (size_t)(c2 * 2 + cg) * 9216 + col * 288 + q * 8;
            *(uint4*)&lwH[col][q * 8] = *(const uint4*)(wpH + gb);
            *(uint4*)&lwL[col][q * 8] = *(const uint4*)(wpL + gb);
        }
        __syncthreads();
        #pragma unroll
        for (int tap = 0; tap < 9; ++tap) {
            const int dy = tap / 3, dx = tap % 3;
            short8 aH[2], aL[2], bH[2], bL[2];
            #pragma unroll
            for (int ct = 0; ct < 2; ++ct) {
                aH[ct] = *(const short8*)&lwH[ct * 16 + l15][tap * 32 + lhi * 8];
                aL[ct] = *(const short8*)&lwL[ct * 16 + l15][tap * 32 + lhi * 8];
            }
            #pragma unroll
            for (int bt = 0; bt < 2; ++bt) {
                bH[bt] = *(const short8*)&linH[wv + dy][bt * 16 + l15 + dx][lhi * 8];
                bL[bt] = *(const short8*)&linL[wv + dy][bt * 16 + l15 + dx][lhi * 8];
            }
            #pragma unroll
            for (int ct = 0; ct < 2; ++ct)
                #pragma unroll
                for (int bt = 0; bt < 2; ++bt) {
                    acc[ct][bt] = __builtin_amdgcn_mfma_f32_16x16x32_bf16(aH[ct], bH[bt], acc[ct][bt], 0, 0, 0);
                    acc[ct][bt] = __builtin_amdgcn_mfma_f32_16x16x32_bf16(aH[ct], bL[bt], acc[ct][bt], 0, 0, 0);
                    acc[ct][bt] = __builtin_amdgcn_mfma_f32_16x16x32_bf16(aL[ct], bH[bt], acc[ct][bt], 0, 0, 0);
                }
        }
    }

    int orow = pxb * 8 + wv;
    #pragma unroll
    for (int ct = 0; ct < 2; ++ct) {
        #pragma unroll
        for (int j = 0; j < 4; ++j) {
            int co_l = ct * 16 + lhi * 4 + j;
            int co = cg * 32 + co_l;
            float bv = bias ? bias[co] : 0.f;
            float s = 0.f, q = 0.f;
            #pragma unroll
            for (int bt = 0; bt < 2; ++bt) {
                float v = acc[ct][bt][j] + bv;
                if (ACT == 1) v = lrelu(v);
                int col = bt * 16 + l15;
                out[(((size_t)n * 64 + co) << 10) + orow * 32 + col] = v;
                if (STATS) { s += v; q = fmaf(v, v, q); }
            }
            if (STATS) {
                #pragma unroll
                for (int m = 1; m < 16; m <<= 1) {
                    s += __shfl_xor(s, m);
                    q += __shfl_xor(q, m);
                }
                if (l15 == 0) { sS[wv][co_l] = s; sQ[wv][co_l] = q; }
            }
        }
    }
    if (STATS) {
        __syncthreads();
        if (tid < 32) {
            float s = 0.f, q = 0.f;
            #pragma unroll
            for (int k = 0; k < 8; ++k) { s += sS[k][tid]; q += sQ[k][tid]; }
            psum[(cg * 32 + tid) * 256 + n * 4 + pxb] = s;
            pss [(cg * 32 + tid) * 256 + n * 4 + pxb] = q;
        }
    }
}

// ================= MFMA conv1x1 64->64 @32x32, bf16 (decoder), prepped weights =================
template<int ACT, int STATS>
__global__ void __launch_bounds__(256) mfma_conv1x1_k(
    const unsigned short* __restrict__ inT, const unsigned short* __restrict__ wp,
    const float* __restrict__ bias, float* __restrict__ out,
    float* __restrict__ psum, float* __restrict__ pss)
{
    __shared__ unsigned short lin[256][72];
    __shared__ unsigned short lwA[32][72];
    __shared__ float sS[4][32], sQ[4][32];
    int b = blockIdx.x;
    int cg = b & 1, pxb = (b >> 1) & 3, n = b >> 3;
    int tid = threadIdx.x;
    int wv = tid >> 6, l = tid & 63;
    int l15 = l & 15, lhi = l >> 4;

    for (int i = tid; i < 2048; i += 256) {
        int px = i >> 3, q = i & 7;
        uint4 v = *(const uint4*)(inT + ((((size_t)n << 10) + pxb * 256 + px) << 6) + q * 8);
        *(uint4*)&lin[px][q * 8] = v;
    }
    for (int i = tid; i < 256; i += 256) {
        int col = i >> 3, q = i & 7;
        *(uint4*)&lwA[col][q * 8] = *(const uint4*)(wp + (size_t)(cg * 32 + col) * 64 + q * 8);
    }
    __syncthreads();

    f32x4 acc[2][4];
    #pragma unroll
    for (int ct = 0; ct < 2; ++ct)
        #pragma unroll
        for (int bt = 0; bt < 4; ++bt) {
            f32x4 z = {0.f, 0.f, 0.f, 0.f};
            acc[ct][bt] = z;
        }

    #pragma unroll
    for (int ks = 0; ks < 2; ++ks) {
        short8 a[2], bb[4];
        #pragma unroll
        for (int ct = 0; ct < 2; ++ct)
            a[ct] = *(const short8*)&lwA[ct * 16 + l15][ks * 32 + lhi * 8];
        #pragma unroll
        for (int bt = 0; bt < 4; ++bt)
            bb[bt] = *(const short8*)&lin[wv * 64 + bt * 16 + l15][ks * 32 + lhi * 8];
        #pragma unroll
        for (int ct = 0; ct < 2; ++ct)
            #pragma unroll
            for (int bt = 0; bt < 4; ++bt)
                acc[ct][bt] = __builtin_amdgcn_mfma_f32_16x16x32_bf16(a[ct], bb[bt], acc[ct][bt], 0, 0, 0);
    }

    #pragma unroll
    for (int ct = 0; ct < 2; ++ct) {
        #pragma unroll
        for (int j = 0; j < 4; ++j) {
            int co_l = ct * 16 + lhi * 4 + j;
            int co = cg * 32 + co_l;
            float bv = bias ? bias[co] : 0.f;
            float s = 0.f, q = 0.f;
            #pragma unroll
            for (int bt = 0; bt < 4; ++bt) {
                float v = acc[ct][bt][j] + bv;
                if (ACT == 1) v = lrelu(v);
                int px = pxb * 256 + wv * 64 + bt * 16 + l15;
                out[(((size_t)n * 64 + co) << 10) + px] = v;
                if (STATS) { s += v; q = fmaf(v, v, q); }
            }
            if (STATS) {
                #pragma unroll
                for (int m = 1; m < 16; m <<= 1) {
                    s += __shfl_xor(s, m);
                    q += __shfl_xor(q, m);
                }
                if (l15 == 0) { sS[wv][co_l] = s; sQ[wv][co_l] = q; }
            }
        }
    }
    if (STATS) {
        __syncthreads();
        if (tid < 32) {
            float s = sS[0][tid] + sS[1][tid] + sS[2][tid] + sS[3][tid];
            float q = sQ[0][tid] + sQ[1][tid] + sQ[2][tid] + sQ[3][tid];
            psum[(cg * 32 + tid) * 256 + n * 4 + pxb] = s;
            pss [(cg * 32 + tid) * 256 + n * 4 + pxb] = q;
        }
    }
}

// ================= MFMA dt1: deconv 64->32, 32x32 -> 64x64, lrelu (bf16), prepped weights =================
__global__ void __launch_bounds__(256) mfma_dt1_k(
    const unsigned short* __restrict__ inT, const unsigned short* __restrict__ wp,
    const float* __restrict__ bias, float* __restrict__ out)
{
    __shared__ unsigned short lin[5][34][40];
    __shared__ unsigned short lwA[2][32][136];
    int b = blockIdx.x;
    int ublk = b & 7, p_y = (b >> 3) & 1, n = b >> 4;
    int tid = threadIdx.x;
    int wv = tid >> 6, l = tid & 63;
    int l15 = l & 15, lhi = l >> 4;
    int pq = wv & 1;
    int vbase = 1 - pq;
    int ubase = ublk * 4 + (p_y == 0 ? 1 : 0);

    f32x4 acc[2][4];
    #pragma unroll
    for (int ct = 0; ct < 2; ++ct)
        #pragma unroll
        for (int bt = 0; bt < 4; ++bt) {
            f32x4 z = {0.f, 0.f, 0.f, 0.f};
            acc[ct][bt] = z;
        }

    for (int ch = 0; ch < 2; ++ch) {
        __syncthreads();
        for (int i = tid; i < 680; i += 256) {
            int rr = i / 136, rem = i % 136;
            int jc = rem >> 2, q = rem & 3;
            int gy = ubase - 1 + rr, gx = jc - 1;
            uint4 v = make_uint4(0u, 0u, 0u, 0u);
            if (gy >= 0 && gy < 32 && gx >= 0 && gx < 32)
                v = *(const uint4*)(inT + ((((size_t)n << 10) + gy * 32 + gx) << 6) + ch * 32 + q * 8);
            *(uint4*)&lin[rr][jc][q * 8] = v;
        }
        for (int i = tid; i < 1024; i += 256) {
            int pqq = i >> 9, co = (i >> 4) & 31, q = i & 15;
            size_t gb = (size_t)(((p_y * 2 + ch) * 2 + pqq) << 12) + co * 128 + q * 8;
            *(uint4*)&lwA[pqq][co][q * 8] = *(const uint4*)(wp + gb);
        }
        __syncthreads();
        #pragma unroll
        for (int ks = 0; ks < 4; ++ks) {
            int ty = ks >> 1, tx = ks & 1;
            short8 a[2], bb[4];
            #pragma unroll
            for (int ct = 0; ct < 2; ++ct)
                a[ct] = *(const short8*)&lwA[pq][ct * 16 + l15][ks * 32 + lhi * 8];
            #pragma unroll
            for (int bt = 0; bt < 4; ++bt) {
                int jloc = (wv >> 1) * 2 + (bt >> 1);
                int vloc = (bt & 1) * 16 + l15;
                bb[bt] = *(const short8*)&lin[jloc + 1 - ty][vloc + vbase + 1 - tx][lhi * 8];
            }
            #pragma unroll
            for (int ct = 0; ct < 2; ++ct)
                #pragma unroll
                for (int bt = 0; bt < 4; ++bt)
                    acc[ct][bt] = __builtin_amdgcn_mfma_f32_16x16x32_bf16(a[ct], bb[bt], acc[ct][bt], 0, 0, 0);
        }
    }

    #pragma unroll
    for (int ct = 0; ct < 2; ++ct) {
        #pragma unroll
        for (int j = 0; j < 4; ++j) {
            int co = ct * 16 + lhi * 4 + j;
            float bv = bias[co];
            #pragma unroll
            for (int bt = 0; bt < 4; ++bt) {
                int jloc = (wv >> 1) * 2 + (bt >> 1);
                int vloc = (bt & 1) * 16 + l15;
                int oy = 2 * (ubase + jloc) - 1 + p_y;
                int ox = 2 * (vloc + vbase) - 1 + pq;
                out[((size_t)(n * 32 + co) << 12) + oy * 64 + ox] = lrelu(acc[ct][bt][j] + bv);
            }
        }
    }
}

// ================= VQ =================
__device__ __forceinline__ unsigned order_u32(float s) {
    unsigned u = __float_as_uint(s);
    return (s < 0.f) ? ~u : (u | 0x80000000u);
}
__device__ __forceinline__ unsigned long long min_u64(unsigned long long a, unsigned long long b) {
    return a < b ? a : b;
}

__global__ void __launch_bounds__(256) vq_prep_k(
    const float* __restrict__ emb,
    unsigned short* __restrict__ eH, unsigned short* __restrict__ eL,
    float* __restrict__ en)
{
    int b = blockIdx.x;
    int tid = threadIdx.x;
    int r = b * 4 + (tid >> 6);
    int d = tid & 63;
    float v = emb[r * 64 + d];
    unsigned short h = f2bf(v);
    eH[r * 64 + d] = h;
    eL[r * 64 + d] = f2bf(v - bf2f(h));
    if (tid < 4) {
        int row = b * 4 + tid;
        const float4* e4 = (const float4*)(emb + (size_t)row * 64);
        float s = 0.f;
        #pragma unroll
        for (int j = 0; j < 16; ++j) {
            float4 e = e4[j];
            s = fmaf(e.x, e.x, s); s = fmaf(e.y, e.y, s);
            s = fmaf(e.z, e.z, s); s = fmaf(e.w, e.w, s);
        }
        en[row] = s;
    }
}

// LDS rows padded to 76 (stride 38 dwords, gcd(38,32)=2 -> 2-way, free)
__global__ void __launch_bounds__(256) vq_dist_mfma_k(
    const float* __restrict__ z,
    const unsigned short* __restrict__ embH, const unsigned short* __restrict__ embL,
    const float* __restrict__ enq,
    unsigned long long* __restrict__ best)
{
    __shared__ unsigned short zH[128][76], zL[128][76];
    __shared__ unsigned short eH[128][76], eL[128][76];
    __shared__ float en[128];
    int b = blockIdx.x;
    int n = b >> 3, pxb = b & 7;
    int tid = threadIdx.x;
    int wv = tid >> 6, l = tid & 63;
    int l15 = l & 15, lhi = l >> 4;

    for (int k = 0; k < 32; ++k) {
        int idx = k * 256 + tid;
        int d = idx >> 7, px = idx & 127;
        float v = z[(size_t)n * 65536 + (size_t)d * 1024 + pxb * 128 + px];
        unsigned short h = f2bf(v);
        zH[px][d] = h;
        zL[px][d] = f2bf(v - bf2f(h));
    }

    unsigned long long bb0 = ~0ULL, bb1 = ~0ULL;

    for (int ch = 0; ch < 4; ++ch) {
        __syncthreads();
        for (int i = tid; i < 1024; i += 256) {
            int kc = i >> 3, q = i & 7;
            size_t gi = (size_t)(ch * 128 + kc) * 64 + q * 8;
            *(uint4*)&eH[kc][q * 8] = *(const uint4*)(embH + gi);
            *(uint4*)&eL[kc][q * 8] = *(const uint4*)(embL + gi);
        }
        if (tid < 128) en[tid] = enq[ch * 128 + tid];
        __syncthreads();

        #pragma unroll
        for (int pt = 0; pt < 2; ++pt) {
            int px = (wv * 2 + pt) * 16 + l15;
            short8 zh0 = *(const short8*)&zH[px][lhi * 8];
            short8 zh1 = *(const short8*)&zH[px][32 + lhi * 8];
            short8 zl0 = *(const short8*)&zL[px][lhi * 8];
            short8 zl1 = *(const short8*)&zL[px][32 + lhi * 8];
            unsigned long long bbl = (pt == 0) ? bb0 : bb1;
            #pragma unroll
            for (int ct2 = 0; ct2 < 8; ++ct2) {
                f32x4 acc = {0.f, 0.f, 0.f, 0.f};
                short8 eh0 = *(const short8*)&eH[ct2 * 16 + l15][lhi * 8];
                short8 eh1 = *(const short8*)&eH[ct2 * 16 + l15][32 + lhi * 8];
                short8 el0 = *(const short8*)&eL[ct2 * 16 + l15][lhi * 8];
                short8 el1 = *(const short8*)&eL[ct2 * 16 + l15][32 + lhi * 8];
                acc = __builtin_amdgcn_mfma_f32_16x16x32_bf16(eh0, zh0, acc, 0, 0, 0);
                acc = __builtin_amdgcn_mfma_f32_16x16x32_bf16(eh1, zh1, acc, 0, 0, 0);
                acc = __builtin_amdgcn_mfma_f32_16x16x32_bf16(eh0, zl0, acc, 0, 0, 0);
                acc = __builtin_amdgcn_mfma_f32_16x16x32_bf16(eh1, zl1, acc, 0, 0, 0);
                acc = __builtin_amdgcn_mfma_f32_16x16x32_bf16(el0, zh0, acc, 0, 0, 0);
                acc = __builtin_amdgcn_mfma_f32_16x16x32_bf16(el1, zh1, acc, 0, 0, 0);
                int kb = ch * 128 + ct2 * 16 + lhi * 4;
                #pragma unroll
                for (int j = 0; j < 4; ++j) {
                    float dist = fmaf(-2.f, acc[j], en[ct2 * 16 + lhi * 4 + j]);
                    unsigned long long p = ((unsigned long long)order_u32(dist) << 32) | (unsigned)(kb + j);
                    bbl = min_u64(bbl, p);
                }
            }
            if (pt == 0) bb0 = bbl; else bb1 = bbl;
        }
    }

    #pragma unroll
    for (int pt = 0; pt < 2; ++pt) {
        unsigned long long v = (pt == 0) ? bb0 : bb1;
        v = min_u64(v, __shfl_xor(v, 16));
        v = min_u64(v, __shfl_xor(v, 32));
        if (lhi == 0) {
            int px = (wv * 2 + pt) * 16 + l15;
            best[(size_t)n * 1024 + pxb * 128 + px] = v;
        }
    }
}

__global__ void __launch_bounds__(256) vq_combine_k(
    const float* __restrict__ z, const float* __restrict__ emb,
    const unsigned long long* __restrict__ best,
    float* __restrict__ out_q, unsigned short* __restrict__ outT,
    float* __restrict__ partials)
{
    __shared__ unsigned tq32[256][33];
    __shared__ float sh[256];
    int tid = threadIdx.x;
    int m = blockIdx.x * 256 + tid;
    unsigned long long bb = best[m];
    int bi = (int)(bb & 0x1ffu);
    int n = m >> 10, p = m & 1023;
    size_t base = (size_t)n * 65536 + p;
    const float* eb = emb + (bi << 6);
    float lsum = 0.f;
    #pragma unroll
    for (int d = 0; d < 64; d += 2) {
        float z0 = z[base + (size_t)d * 1024];
        float z1 = z[base + (size_t)(d + 1) * 1024];
        float q0 = eb[d], q1 = eb[d + 1];
        out_q[base + (size_t)d * 1024]       = q0;
        out_q[base + (size_t)(d + 1) * 1024] = q1;
        float d0 = q0 - z0, d1 = q1 - z1;
        lsum = fmaf(d0, d0, lsum);
        lsum = fmaf(d1, d1, lsum);
        tq32[tid][d >> 1] = (unsigned)f2bf(q0) | ((unsigned)f2bf(q1) << 16);
    }
    sh[tid] = lsum;
    __syncthreads();
    unsigned* oT = (unsigned*)outT;
    size_t m0 = (size_t)blockIdx.x * 256;
    #pragma unroll
    for (int k = 0; k < 32; ++k) {
        int j = k * 256 + tid;
        int px = j >> 5, c = j & 31;
        oT[(m0 + px) * 32 + c] = tq32[px][c];
    }
    for (int st = 128; st > 0; st >>= 1) {
        if (tid < st) sh[tid] += sh[tid + st];
        __syncthreads();
    }
    if (tid == 0) partials[blockIdx.x] = sh[0];
}

__global__ void vq_fin_k(const float* __restrict__ partials, float* __restrict__ out)
{
    __shared__ float sh[256];
    sh[threadIdx.x] = partials[threadIdx.x];
    __syncthreads();
    for (int st = 128; st > 0; st >>= 1) {
        if (threadIdx.x < st) sh[threadIdx.x] += sh[threadIdx.x + st];
        __syncthreads();
    }
    if (threadIdx.x == 0) out[0] = sh[0] * (0.25f / (65536.f * 64.f));
}

// ================= dt2: deconv 32->3, 64x64 -> 128x128, tanh (fp32) =================
__global__ void __launch_bounds__(256) deconv_dt2_t(
    const float* __restrict__ in, const float* __restrict__ w,
    const float* __restrict__ bias, float* __restrict__ out)
{
    __shared__ float lin[8][4][67];
    __shared__ float lw[8][3][16];
    int b = blockIdx.x;
    int n = b & 63, rt = b >> 6;
    int tid = threadIdx.x;
    int r4 = tid >> 6, g = tid & 63;
    int oy = rt * 4 + r4;
    const float* inp = in + (size_t)n * 32 * 4096;
    int iy0 = 2 * rt - 1;
    int ky0 = (oy + 1) & 1;
    int iyA = ((oy + 1 - ky0) >> 1) - iy0;
    int iyB = iyA - 1;

    if (tid < 64) lin[tid >> 3][(tid >> 1) & 3][(tid & 1) ? 65 : 0] = 0.f;

    float acc[3][2];
    #pragma unroll
    for (int co = 0; co < 3; ++co) { acc[co][0] = acc[co][1] = 0.f; }

    int scol = tid & 63, srs = tid >> 6;
    for (int cic = 0; cic < 4; ++cic) {
        __syncthreads();
        {
            int gy = iy0 + srs;
            bool ok = (gy >= 0 && gy < 64);
            #pragma unroll
            for (int k = 0; k < 8; ++k) {
                float v = ok ? inp[(cic * 8 + k) * 4096 + gy * 64 + scol] : 0.f;
                lin[k][srs][scol + 1] = v;
            }
        }
        if (tid < 128) {
            int ci = tid >> 4, tt = tid & 15;
            #pragma unroll
            for (int co = 0; co < 3; ++co)
                lw[ci][co][tt] = w[((cic * 8 + ci) * 3 + co) * 16 + tt];
        }
        __syncthreads();
        #pragma unroll 2
        for (int ci = 0; ci < 8; ++ci) {
            float vA0 = lin[ci][iyA][g],     vA1 = lin[ci][iyA][g + 1], vA2 = lin[ci][iyA][g + 2];
            float vB0 = lin[ci][iyB][g],     vB1 = lin[ci][iyB][g + 1], vB2 = lin[ci][iyB][g + 2];
            #pragma unroll
            for (int co = 0; co < 3; ++co) {
                const float4* wp = (const float4*)lw[ci][co];
                float4 wA = wp[ky0];
                float4 wB = wp[ky0 + 2];
                acc[co][0] = fmaf(vA1, wA.y, fmaf(vA0, wA.w, fmaf(vB1, wB.y, fmaf(vB0, wB.w, acc[co][0]))));
                acc[co][1] = fmaf(vA2, wA.x, fmaf(vA1, wA.z, fmaf(vB2, wB.x, fmaf(vB1, wB.z, acc[co][1]))));
            }
        }
    }
    #pragma unroll
    for (int co = 0; co < 3; ++co) {
        float bv = bias[co];
        float2 v;
        v.x = fast_tanh(acc[co][0] + bv);
        v.y = fast_tanh(acc[co][1] + bv);
        *(float2*)(out + ((size_t)(n * 3 + co) * 16384) + oy * 128 + 2 * g) = v;
    }
}

extern "C" void kernel_launch(void* const* d_in, const int* in_sizes, int n_in,
                              void* d_out, int out_size, void* d_ws, size_t ws_size,
                              hipStream_t stream)
{
    const float* x    = (const float*)d_in[0];
    const float* e1w  = (const float*)d_in[1];
    const float* e1b  = (const float*)d_in[2];
    const float* e2w  = (const float*)d_in[3];
    const float* e2b  = (const float*)d_in[4];
    const float* e3w  = (const float*)d_in[5];
    const float* e3b  = (const float*)d_in[6];
    const float* er1w = (const float*)d_in[7];
    const float* er1g = (const float*)d_in[8];
    const float* er1b = (const float*)d_in[9];
    const float* er2w = (const float*)d_in[10];
    const float* er2g = (const float*)d_in[11];
    const float* er2b = (const float*)d_in[12];
    const float* e4w  = (const float*)d_in[13];
    const float* e4b  = (const float*)d_in[14];
    const float* emb  = (const float*)d_in[15];
    const float* d1w  = (const float*)d_in[16];
    const float* d1b  = (const float*)d_in[17];
    const float* dr1w = (const float*)d_in[18];
    const float* dr1g = (const float*)d_in[19];
    const float* dr1b = (const float*)d_in[20];
    const float* dr2w = (const float*)d_in[21];
    const float* dr2g = (const float*)d_in[22];
    const float* dr2b = (const float*)d_in[23];
    const float* dt1w = (const float*)d_in[24];
    const float* dt1b = (const float*)d_in[25];
    const float* dt2w = (const float*)d_in[26];
    const float* dt2b = (const float*)d_in[27];

    float* out = (float*)d_out;
    float* ws  = (float*)d_ws;

    // workspace layout (floats)
    float* B0 = ws;                   // 8,388,608
    float* B1 = ws + 8388608;         // 4,194,304
    float* B2 = B1 + 4194304;
    float* B3 = B2 + 4194304;
    float* B4 = B3 + 4194304;
    float* psum   = B4 + 4194304;     // 32768
    float* pss    = psum + 32768;     // 32768
    float* fin    = pss + 32768;      // 128
    float* vq_part = fin + 128;       // 256
    unsigned long long* bestbuf = (unsigned long long*)(vq_part + 256);  // 65536 u64 = 512KB
    unsigned short* embH = (unsigned short*)(bestbuf + 65536);           // 32768 ushorts
    unsigned short* embL = embH + 32768;                                 // 32768 ushorts
    float* enq = (float*)(embL + 32768);                                 // 512 floats
    unsigned short* e3wH  = (unsigned short*)(enq + 512);                // 36864
    unsigned short* e3wL  = e3wH + 36864;
    unsigned short* er1wH = e3wL + 36864;
    unsigned short* er1wL = er1wH + 36864;
    unsigned short* d1wH  = er1wL + 36864;
    unsigned short* dr1wH = d1wH + 36864;
    unsigned short* e2wH  = dr1wH + 36864;                               // 32768
    unsigned short* e2wL  = e2wH + 32768;
    unsigned short* dt1wp = e2wL + 32768;                                // 32768
    unsigned short* dr2wp = dt1wp + 32768;                               // 4096

    unsigned short* e1H  = (unsigned short*)B0;            // 8,388,608 ushorts
    unsigned short* e1L  = e1H + 8388608;                  // 8,388,608 ushorts
    unsigned short* tbuf  = (unsigned short*)B1;           // decoder NHWC bf16
    unsigned short* tbufH = (unsigned short*)B3;           // encoder split-bf16 hi
    unsigned short* tbufL = (unsigned short*)B4;           // encoder split-bf16 lo

    float* out_recon = out;                 // 3,145,728
    float* out_q     = out + 3145728;       // 4,194,304
    float* out_e     = out + 7340032;       // 4,194,304 (scratch until e4 writes)
    float* out_loss  = out + 11534336;      // 1

    const float invM = 1.f / 65536.f;

    // ---------------- preps ----------------
    wprep_k<<<848, 256, 0, stream>>>(e3w, er1w, d1w, dr1w, e2w, dt1w, dr2w,
                                     e3wH, e3wL, er1wH, er1wL, d1wH, dr1wH, e2wH, e2wL,
                                     dt1wp, dr2wp);
    vq_prep_k<<<128, 256, 0, stream>>>(emb, embH, embL, enq);

    // ---------------- encoder ----------------
    conv_e1_t<<<1024, 256, 0, stream>>>(x, e1w, e1b, e1H, e1L);
    mfma_e2_k<<<256, 512, 0, stream>>>(e1H, e1L, e2wH, e2wL, e2b, tbufH, tbufL);

    mfma_conv3x3_hl_k<1,0><<<512, 512, 0, stream>>>(tbufH, tbufL, e3wH, e3wL, e3b, B2, nullptr, nullptr);

    trans_hl_k<0><<<256, 256, 0, stream>>>(B2, nullptr, nullptr, tbufH, tbufL);
    mfma_conv3x3_hl_k<0,1><<<512, 512, 0, stream>>>(tbufH, tbufL, er1wH, er1wL, nullptr, B1, psum, pss);
    bn_fin3_k<<<1, 64, 0, stream>>>(psum, pss, fin, invM);

    conv1x1_t<1,0,1><<<512, 256, 0, stream>>>(B1, nullptr, er2w, nullptr, fin, er1g, er1b, B4, psum, pss);
    bn_fin2_k<<<1, 256, 0, stream>>>(psum, pss, fin, invM, 512);
    conv1x1_t<2,1,0><<<512, 256, 0, stream>>>(B4, B2, e4w, e4b, fin, er2g, er2b, out_e, nullptr, nullptr);

    // VQ
    vq_dist_mfma_k<<<512, 256, 0, stream>>>(out_e, embH, embL, enq, bestbuf);
    vq_combine_k<<<256, 256, 0, stream>>>(out_e, emb, bestbuf, out_q, tbuf, vq_part);
    vq_fin_k<<<1, 256, 0, stream>>>(vq_part, out_loss);

    // ---------------- decoder (bf16 MFMA) ----------------
    mfma_conv3x3_k<1,0><<<512, 512, 0, stream>>>(tbuf, d1wH, d1b, B2, nullptr, nullptr);

    trans_k<0><<<256, 256, 0, stream>>>(B2, nullptr, nullptr, nullptr, tbuf);
    mfma_conv3x3_k<0,1><<<512, 512, 0, stream>>>(tbuf, dr1wH, nullptr, B3, psum, pss);
    bn_fin3_k<<<1, 64, 0, stream>>>(psum, pss, fin, invM);

    trans_k<1><<<256, 256, 0, stream>>>(B3, fin, dr1g, dr1b, tbuf);
    mfma_conv1x1_k<0,1><<<512, 256, 0, stream>>>(tbuf, dr2wp, nullptr, B4, psum, pss);
    bn_fin3_k<<<1, 64, 0, stream>>>(psum, pss, fin, invM);

    bnres_trans_k<<<256, 256, 0, stream>>>(B4, B2, fin, dr2g, dr2b, tbuf);
    mfma_dt1_k<<<1024, 256, 0, stream>>>(tbuf, dt1wp, dt1b, B0);

    deconv_dt2_t<<<2048, 256, 0, stream>>>(B0, dt2w, dt2b, out_recon);
}